// Round 13
// baseline (6085.091 us; speedup 1.0000x reference)
//
#include <hip/hip_runtime.h>
#include <hip/hip_bf16.h>
#include <cstdint>
#include <cstddef>

#define B_ 32
#define S_ 512
#define D_ 256
#define H_ 512

typedef _Float16 h2 __attribute__((ext_vector_type(2)));
typedef _Float16 h4 __attribute__((ext_vector_type(4)));
typedef _Float16 h8 __attribute__((ext_vector_type(8)));
typedef float f32x4 __attribute__((ext_vector_type(4)));
typedef unsigned u32x4 __attribute__((ext_vector_type(4)));

__device__ __forceinline__ h2 H2(unsigned u) { return __builtin_bit_cast(h2, u); }
__device__ __forceinline__ unsigned U2(h2 v) { return __builtin_bit_cast(unsigned, v); }

#if __has_builtin(__builtin_amdgcn_fdot2)
__device__ __forceinline__ float dot2f(h2 a, h2 b, float c) {
  return __builtin_amdgcn_fdot2(a, b, c, false);
}
#else
__device__ __forceinline__ float dot2f(h2 a, h2 b, float c) {
  return c + (float)a.x * (float)b.x + (float)a.y * (float)b.y;
}
#endif

#if __has_builtin(__builtin_amdgcn_exp2f)
__device__ __forceinline__ float exp2_fast(float x) { return __builtin_amdgcn_exp2f(x); }
#else
__device__ __forceinline__ float exp2_fast(float x) { return exp2f(x); }
#endif
#if __has_builtin(__builtin_amdgcn_rcpf)
__device__ __forceinline__ float rcp_fast(float x) { return __builtin_amdgcn_rcpf(x); }
#else
__device__ __forceinline__ float rcp_fast(float x) { return 1.0f / x; }
#endif

__device__ __forceinline__ float sigm(float x) {
  return rcp_fast(1.0f + exp2_fast(-1.4426950408889634f * x));
}
__device__ __forceinline__ float tanh_fast(float x) {
  return 1.0f - 2.0f * rcp_fast(1.0f + exp2_fast(2.8853900817779268f * x));
}

// Coherent 16B load (bypass L1/L2, read L3). Caller MUST vm_drain() before use.
__device__ __forceinline__ uint4 coh_load16(const void* p) {
  u32x4 v;
  asm volatile("global_load_dwordx4 %0, %1, off sc0 sc1"
               : "=v"(v) : "v"(p) : "memory");
  return __builtin_bit_cast(uint4, v);
}
// Coherent 16B write-through store (vector-typed input: valid 'v' constraint).
__device__ __forceinline__ void coh_store16(void* p, u32x4 v) {
  asm volatile("global_store_dwordx4 %0, %1, off sc0 sc1"
               :: "v"(p), "v"(v) : "memory");
}
__device__ __forceinline__ void vm_drain() {
  asm volatile("s_waitcnt vmcnt(0)" ::: "memory");
}

// Sentinel = 0xFFFF per fp16 (a NaN). Legal h values are sigm*tanh in (-1,1)
// -> never NaN -> never 0xFFFF.
__device__ __forceinline__ bool valid16(uint4 v) {
  return ((v.x & 0xFFFFu) != 0xFFFFu) && ((v.x >> 16) != 0xFFFFu) &&
         ((v.y & 0xFFFFu) != 0xFFFFu) && ((v.y >> 16) != 0xFFFFu) &&
         ((v.z & 0xFFFFu) != 0xFFFFu) && ((v.z >> 16) != 0xFFFFu) &&
         ((v.w & 0xFFFFu) != 0xFFFFu) && ((v.w >> 16) != 0xFFFFu);
}

// Publish one batch-row of 8 halves as ONE dwordx4 write-through store.
// Must be called with the owning wave's lanes (lane = cb*8 + cc) active.
// 5 shfls pack in-register; lane cb*8 stores 16B. No LDS, no barrier.
__device__ __forceinline__ void publish8(int lane, unsigned short hval,
                                         unsigned short* dst_base /*lane&7==0's dst*/) {
  unsigned hv = hval;
  unsigned ot = (unsigned)__shfl((int)hv, lane ^ 1, 64);
  unsigned pk = (hv & 0xFFFFu) | (ot << 16);   // valid on even lanes
  int base = lane & ~7;
  u32x4 v;
  v.x = (unsigned)__shfl((int)pk, base + 0, 64);
  v.y = (unsigned)__shfl((int)pk, base + 2, 64);
  v.z = (unsigned)__shfl((int)pk, base + 4, 64);
  v.w = (unsigned)__shfl((int)pk, base + 6, 64);
  if ((lane & 7) == 0) coh_store16(dst_base, v);
}

// fill a region with the sentinel pattern (grid-stride, uint4 granularity)
__global__ __launch_bounds__(256) void fill_sent_k(uint4* __restrict__ dst, size_t n16) {
  uint4 s = {0xFFFFFFFFu, 0xFFFFFFFFu, 0xFFFFFFFFu, 0xFFFFFFFFu};
  size_t stride = (size_t)gridDim.x * 256;
  for (size_t i = (size_t)blockIdx.x * 256 + threadIdx.x; i < n16; i += stride)
    dst[i] = s;
}

// fp32 -> fp16 convert (4 elems/thread)
__global__ __launch_bounds__(256) void f2h_k(const float* __restrict__ src,
                                             _Float16* __restrict__ dst, int n4) {
  int i = blockIdx.x * 256 + threadIdx.x;
  if (i < n4) {
    float4 v = ((const float4*)src)[i];
    h4 o = {(_Float16)v.x, (_Float16)v.y, (_Float16)v.z, (_Float16)v.w};
    ((h4*)dst)[i] = o;
  }
}

// ---------------- persistent encoder: MFMA + sentinel dataflow sync ---------
// 512 blocks = 8 groups (dir x 4 batch-quarters of 8) x 64 blocks.
// Block: 8 h-cols x 4 gates; wave = gate. MFMA 16x16x32, A rows 8..15 zero.
// NO barriers: consumers poll h slots; producers publish 16B coalesced.
__global__ __launch_bounds__(256, 1) void enc_coop_k(
    const _Float16* __restrict__ xh,
    const _Float16* __restrict__ WihF, const _Float16* __restrict__ WhhF, const float* __restrict__ bF,
    const _Float16* __restrict__ WihR, const _Float16* __restrict__ WhhR, const float* __restrict__ bR,
    float* __restrict__ cF, float* __restrict__ cR,
    _Float16* __restrict__ hsF, _Float16* __restrict__ hsR)
{
  __shared__ __align__(16) _Float16 cbuf[96][16][8];  // [k8][n][8]; n>=8 dead
  __shared__ float zfin[4][8][9];
  __shared__ float cls[8][9];

  const int bid = blockIdx.x;
  const int group = bid >> 6;       // 0..7 = dir*4 + quarter
  const int dir = group >> 2;
  const int q8 = (group & 3) << 3;  // batch base (8 batches per group)
  const int jb = bid & 63;
  const int c0 = jb << 3;           // 8 h-cols per block
  const int tid = threadIdx.x;
  const int lane = tid & 63;
  const int wv = tid >> 6;          // wave = gate 0..3

  const _Float16* __restrict__ Wih = dir ? WihR : WihF;
  const _Float16* __restrict__ Whh = dir ? WhhR : WhhF;
  const float* __restrict__ bias = dir ? bR : bF;
  _Float16* __restrict__ hs = dir ? hsR : hsF;
  float* __restrict__ cOut = dir ? cR : cF;

  for (int i = tid; i < 1536; i += 256) {   // zero cbuf (n>=8 cols stay zero)
    uint4 z = {0, 0, 0, 0};
    ((uint4*)cbuf)[i] = z;
  }

  // A-fragments: lane holds W'[row = c0 + (lane&15), gate wv][k-octet lane>>4]
  h8 aw[24];
  {
    const int m = lane & 15, kg = lane >> 4;
    const h8 zz = {0, 0, 0, 0, 0, 0, 0, 0};
    const int wrow = wv * H_ + c0 + (m & 7);
    const _Float16* wi = Wih + (size_t)wrow * D_;
    const _Float16* wh = Whh + (size_t)wrow * H_;
    #pragma unroll
    for (int tu = 0; tu < 24; ++tu) {
      int k = tu * 32 + kg * 8;
      h8 w = (k < 256) ? *(const h8*)(wi + k) : *(const h8*)(wh + (k - 256));
      aw[tu] = (m < 8) ? w : zz;
    }
  }

  const int cc = tid & 7, cb = tid >> 3;  // cell identity (tid<64 -> wave 0)
  float bvg[4];
  #pragma unroll
  for (int g = 0; g < 4; ++g) bvg[g] = bias[g * H_ + c0 + cc];

  const char* cbase = (const char*)cbuf + (size_t)((lane >> 4) * 256 + (lane & 15) * 16);
  const int sn = tid & 7, k8b = (tid >> 3) * 3;   // staging: batch sn, 3 octets
  __syncthreads();

  for (int t = 0; t < S_; ++t) {
    const int xi = dir ? (S_ - 1 - t) : t;
    {  // ---- stage [x ; h_{t-1}]: x via cached loads, h via sentinel poll
      uint4 vs[3];
      unsigned pend = 0;
      #pragma unroll
      for (int u = 0; u < 3; ++u) {
        const int k8 = k8b + u;
        if (k8 < 32) {
          vs[u] = *(const uint4*)(xh + ((size_t)(q8 + sn) * S_ + xi) * D_ + k8 * 8);
        } else if (t == 0) {
          uint4 z = {0, 0, 0, 0};
          vs[u] = z;
        } else {
          pend |= 1u << u;
        }
      }
      if (pend) {
        const int xip = dir ? xi + 1 : xi - 1;
        const _Float16* hbase = hs + ((size_t)xip * B_ + q8 + sn) * H_;
        do {
          #pragma unroll
          for (int u = 0; u < 3; ++u)
            if (pend & (1u << u))
              vs[u] = coh_load16(hbase + (k8b + u - 32) * 8);
          vm_drain();
          #pragma unroll
          for (int u = 0; u < 3; ++u)
            if ((pend & (1u << u)) && valid16(vs[u])) pend &= ~(1u << u);
        } while (pend);
      }
      vm_drain();
      #pragma unroll
      for (int u = 0; u < 3; ++u) *(uint4*)&cbuf[k8b + u][sn][0] = vs[u];
    }
    __syncthreads();

    f32x4 acc = {0.f, 0.f, 0.f, 0.f};
    #pragma unroll
    for (int tu = 0; tu < 24; ++tu) {
      h8 bf = *(const h8*)(cbase + tu * 1024);
      acc = __builtin_amdgcn_mfma_f32_16x16x32_f16(aw[tu], bf, acc, 0, 0, 0);
    }
    {  // D: col(lane&15)=batch, row=(lane>>4)*4+r = block col; keep <8 only
      const int mrow = (lane >> 4) * 4, n = lane & 15;
      if (mrow < 8 && n < 8) {
        #pragma unroll
        for (int r = 0; r < 4; ++r) zfin[wv][mrow + r][n] = acc[r];
      }
    }
    __syncthreads();

    if (tid < 64) {  // cell: 8 cols x 8 batches, all in wave 0
      const float zi = zfin[0][cc][cb] + bvg[0];
      const float zf = zfin[1][cc][cb] + bvg[1];
      const float zg = zfin[2][cc][cb] + bvg[2];
      const float zo = zfin[3][cc][cb] + bvg[3];
      const float c_old = (t == 0) ? 0.f : cls[cc][cb];
      const float cn = sigm(zf) * c_old + sigm(zi) * tanh_fast(zg);
      const float hn = sigm(zo) * tanh_fast(cn);
      cls[cc][cb] = cn;
      _Float16 hh = (_Float16)hn;
      // publish this batch-row (8 halves) as one 16B write-through store
      publish8(lane, __builtin_bit_cast(unsigned short, hh),
               (unsigned short*)(hs + ((size_t)xi * B_ + q8 + cb) * H_ + c0));
      if (t == S_ - 1) cOut[(size_t)(q8 + cb) * H_ + c0 + cc] = cn;
    }
    // no barrier: next iteration's staging polls the data itself
  }
}

// ---------------- persistent decoder: MFMA + sentinel dataflow sync ---------
// 512 blocks = 8 groups (4 batches) x 64 blocks; block: 8 h-cols x 4 gates.
__global__ __launch_bounds__(256, 1) void dec_coop_k(
    const float* __restrict__ hd0, const float* __restrict__ cD0,
    const _Float16* __restrict__ Whh, const float* __restrict__ bias,
    _Float16* __restrict__ hdec)
{
  __shared__ __align__(16) _Float16 cbuf[64][16][8];  // [k8][n][8]; n>=4 dead
  __shared__ float zfin[4][8][5];
  __shared__ float cls[8][5];

  const int bid = blockIdx.x;
  const int group = bid >> 6;       // 0..7: batches group*4 .. +3
  const int g4 = group << 2;
  const int jb = bid & 63;
  const int c0 = jb << 3;
  const int tid = threadIdx.x;
  const int lane = tid & 63;
  const int wv = tid >> 6;
  (void)jb;

  for (int i = tid; i < 1024; i += 256) {
    uint4 z = {0, 0, 0, 0};
    ((uint4*)cbuf)[i] = z;
  }

  h8 aw[16];
  {
    const int m = lane & 15, kg = lane >> 4;
    const h8 zz = {0, 0, 0, 0, 0, 0, 0, 0};
    const _Float16* wh = Whh + (size_t)(wv * H_ + c0 + (m & 7)) * H_;
    #pragma unroll
    for (int tu = 0; tu < 16; ++tu) {
      h8 w = *(const h8*)(wh + tu * 32 + kg * 8);
      aw[tu] = (m < 8) ? w : zz;
    }
  }

  const int cc = tid & 7, cb = tid >> 3;  // cell identity (tid<32 -> wave 0)
  float bvg[4];
  #pragma unroll
  for (int g = 0; g < 4; ++g) bvg[g] = bias[g * H_ + c0 + cc];
  if (tid < 32) cls[cc][cb] = cD0[(size_t)(g4 + cb) * H_ + c0 + cc];

  const char* cbase = (const char*)cbuf + (size_t)((lane >> 4) * 256 + (lane & 15) * 16);
  const int sn = tid & 3, k8 = tid >> 2;  // staging: batch sn, octet k8 (0..63)
  __syncthreads();

  for (int t = 0; t < S_; ++t) {
    {  // stage h_{t-1}: t=0 from hd0 (fp32), else sentinel-poll hdec[t-1]
      if (t == 0) {
        const float* src = hd0 + (size_t)(g4 + sn) * H_ + k8 * 8;
        float4 f0 = *(const float4*)src;
        float4 f1 = *(const float4*)(src + 4);
        h8 o = {(_Float16)f0.x, (_Float16)f0.y, (_Float16)f0.z, (_Float16)f0.w,
                (_Float16)f1.x, (_Float16)f1.y, (_Float16)f1.z, (_Float16)f1.w};
        *(h8*)&cbuf[k8][sn][0] = o;
      } else {
        const _Float16* src = hdec + ((size_t)(t - 1) * B_ + g4 + sn) * H_ + k8 * 8;
        uint4 v;
        do {
          v = coh_load16(src);
          vm_drain();
        } while (!valid16(v));
        *(uint4*)&cbuf[k8][sn][0] = v;
      }
    }
    __syncthreads();

    f32x4 acc = {0.f, 0.f, 0.f, 0.f};
    #pragma unroll
    for (int tu = 0; tu < 16; ++tu) {
      h8 bf = *(const h8*)(cbase + tu * 1024);
      acc = __builtin_amdgcn_mfma_f32_16x16x32_f16(aw[tu], bf, acc, 0, 0, 0);
    }
    {
      const int mrow = (lane >> 4) * 4, n = lane & 15;
      if (mrow < 8 && n < 4) {
        #pragma unroll
        for (int r = 0; r < 4; ++r) zfin[wv][mrow + r][n] = acc[r];
      }
    }
    __syncthreads();

    if (tid < 32) {  // cell: 8 cols x 4 batches, lanes 0..31 of wave 0
      const float zi = zfin[0][cc][cb] + bvg[0];
      const float zf = zfin[1][cc][cb] + bvg[1];
      const float zg = zfin[2][cc][cb] + bvg[2];
      const float zo = zfin[3][cc][cb] + bvg[3];
      const float cn = sigm(zf) * cls[cc][cb] + sigm(zi) * tanh_fast(zg);
      const float hn = sigm(zo) * tanh_fast(cn);
      cls[cc][cb] = cn;
      _Float16 hh = (_Float16)hn;
      publish8(lane, __builtin_bit_cast(unsigned short, hh),
               (unsigned short*)(hdec + ((size_t)t * B_ + g4 + cb) * H_ + c0));
    }
    // no barrier
  }
}

// ---------------- fp16 dot2 tiled GEMM: C[M,512] = op(A)@W^T + bias ----------
template <int MODE>
__global__ __launch_bounds__(256) void gemm_h_k(
    const _Float16* __restrict__ A1, const _Float16* __restrict__ A2,
    const _Float16* __restrict__ W, const float* __restrict__ bias,
    _Float16* __restrict__ C)
{
  __shared__ h2 As2[16][68];
  __shared__ h2 Bs2[16][68];
  const int tid = threadIdx.x;
  const int m0 = blockIdx.x * 64, n0 = blockIdx.y * 64;
  const int tn = tid & 15, tm = tid >> 4;
  float acc[4][4] = {};

  for (int kc = 0; kc < H_; kc += 32) {
    __syncthreads();
    {
      int mm = tid >> 2, q = tid & 3;
      uint4 a = *(const uint4*)(A1 + (size_t)(m0 + mm) * H_ + kc + q * 8);
      if (MODE == 1) {
        uint4 a2 = *(const uint4*)(A2 + (size_t)(m0 + mm) * H_ + kc + q * 8);
        a.x = U2(H2(a.x) + H2(a2.x)); a.y = U2(H2(a.y) + H2(a2.y));
        a.z = U2(H2(a.z) + H2(a2.z)); a.w = U2(H2(a.w) + H2(a2.w));
      }
      As2[q * 4 + 0][mm] = H2(a.x); As2[q * 4 + 1][mm] = H2(a.y);
      As2[q * 4 + 2][mm] = H2(a.z); As2[q * 4 + 3][mm] = H2(a.w);
      uint4 b = *(const uint4*)(W + (size_t)(n0 + mm) * H_ + kc + q * 8);
      Bs2[q * 4 + 0][mm] = H2(b.x); Bs2[q * 4 + 1][mm] = H2(b.y);
      Bs2[q * 4 + 2][mm] = H2(b.z); Bs2[q * 4 + 3][mm] = H2(b.w);
    }
    __syncthreads();
    #pragma unroll
    for (int k2 = 0; k2 < 16; ++k2) {
      uint4 au = *(const uint4*)&As2[k2][tm * 4];
      uint4 bu = *(const uint4*)&Bs2[k2][tn * 4];
      h2 a[4] = {H2(au.x), H2(au.y), H2(au.z), H2(au.w)};
      h2 b[4] = {H2(bu.x), H2(bu.y), H2(bu.z), H2(bu.w)};
      #pragma unroll
      for (int i = 0; i < 4; ++i)
        #pragma unroll
        for (int j = 0; j < 4; ++j)
          acc[i][j] = dot2f(a[i], b[j], acc[i][j]);
    }
  }
  float4 bl = *(const float4*)(bias + n0 + tn * 4);
  #pragma unroll
  for (int i = 0; i < 4; ++i) {
    h2 p0 = {(_Float16)(acc[i][0] + bl.x), (_Float16)(acc[i][1] + bl.y)};
    h2 p1 = {(_Float16)(acc[i][2] + bl.z), (_Float16)(acc[i][3] + bl.w)};
    uint2 st = {U2(p0), U2(p1)};
    *(uint2*)(C + (size_t)(m0 + tm * 4 + i) * H_ + n0 + tn * 4) = st;
  }
}

__device__ __forceinline__ float4 load4f(const float* p) { return *(const float4*)p; }
__device__ __forceinline__ float4 load4f(const _Float16* p) {
  uint2 u = *(const uint2*)p;
  h2 a = H2(u.x), b = H2(u.y);
  return make_float4((float)a.x, (float)a.y, (float)b.x, (float)b.y);
}

// small: C[32,512] = concat(A1,A2)@W^T + bias (K = 1024, halves of 512)
template <typename T>
__global__ __launch_bounds__(256) void gemm_cat_small_k(
    const T* __restrict__ A1, const T* __restrict__ A2,
    const float* __restrict__ W, const float* __restrict__ bias,
    float* __restrict__ C)
{
  const int tid = threadIdx.x;
  const int col = tid & 31;
  const int rg  = tid >> 5;
  const int n   = blockIdx.y * 32 + col;
  float acc[4] = {0, 0, 0, 0};
  #pragma unroll
  for (int pass = 0; pass < 2; ++pass) {
    const T* __restrict__ A = pass ? A2 : A1;
    const float4* __restrict__ w4 = (const float4*)(W + (size_t)n * 1024 + pass * 512);
    for (int k4 = 0; k4 < 128; ++k4) {
      float4 w = w4[k4];
      #pragma unroll
      for (int i = 0; i < 4; ++i) {
        int row = rg + (i << 3);
        float4 a = load4f(A + (size_t)row * H_ + k4 * 4);
        acc[i] += w.x * a.x + w.y * a.y + w.z * a.z + w.w * a.w;
      }
    }
  }
  const float bv = bias[n];
  #pragma unroll
  for (int i = 0; i < 4; ++i) {
    int row = rg + (i << 3);
    C[(size_t)row * H_ + n] = acc[i] + bv;
  }
}

// logits[b, t, s] = bvt + sum_h vt[h] * tanh(pre1[s,b,h] + Q[t,b,h])
__global__ __launch_bounds__(256) void attn_k(
    const _Float16* __restrict__ pre1, const _Float16* __restrict__ Qm,
    const float* __restrict__ vt, const float* __restrict__ bvt,
    float* __restrict__ out)
{
  __shared__ float sp[16][260];
  __shared__ float sq[16][260];
  __shared__ float sv[256];
  const int b = blockIdx.z, tbase = blockIdx.y << 4, sbase = blockIdx.x << 4;
  const int tid = threadIdx.x;
  const int so = tid & 15;
  const int to = tid >> 4;
  float acc = 0.f;

  for (int h0 = 0; h0 < H_; h0 += 256) {
    __syncthreads();
    {
      int i = tid >> 4, off = (tid & 15) * 16;
      uint4 q0 = *(const uint4*)(Qm + ((size_t)(tbase + i) * B_ + b) * H_ + h0 + off);
      uint4 q1 = *(const uint4*)(Qm + ((size_t)(tbase + i) * B_ + b) * H_ + h0 + off + 8);
      uint4 p0 = *(const uint4*)(pre1 + ((size_t)(sbase + i) * B_ + b) * H_ + h0 + off);
      uint4 p1 = *(const uint4*)(pre1 + ((size_t)(sbase + i) * B_ + b) * H_ + h0 + off + 8);
      const unsigned* qs = (const unsigned*)&q0;
      const unsigned* ps = (const unsigned*)&p0;
      #pragma unroll
      for (int u = 0; u < 4; ++u) {
        h2 qv = H2(qs[u]), pv = H2(ps[u]);
        sq[i][off + u * 2] = (float)qv.x; sq[i][off + u * 2 + 1] = (float)qv.y;
        sp[i][off + u * 2] = (float)pv.x; sp[i][off + u * 2 + 1] = (float)pv.y;
      }
      const unsigned* qs2 = (const unsigned*)&q1;
      const unsigned* ps2 = (const unsigned*)&p1;
      #pragma unroll
      for (int u = 0; u < 4; ++u) {
        h2 qv = H2(qs2[u]), pv = H2(ps2[u]);
        sq[i][off + 8 + u * 2] = (float)qv.x; sq[i][off + 8 + u * 2 + 1] = (float)qv.y;
        sp[i][off + 8 + u * 2] = (float)pv.x; sp[i][off + 8 + u * 2 + 1] = (float)pv.y;
      }
    }
    sv[tid] = vt[h0 + tid];
    __syncthreads();
    #pragma unroll 4
    for (int h = 0; h < 256; ++h)
      acc += sv[h] * tanh_fast(sp[so][h] + sq[to][h]);
  }
  out[((size_t)b * S_ + tbase + to) * S_ + sbase + so] = acc + bvt[0];
}

extern "C" void kernel_launch(void* const* d_in, const int* in_sizes, int n_in,
                              void* d_out, int out_size, void* d_ws, size_t ws_size,
                              hipStream_t stream)
{
  (void)in_sizes; (void)n_in; (void)out_size; (void)ws_size;
  const float* x     = (const float*)d_in[0];
  const float* WihF  = (const float*)d_in[1];
  const float* WhhF  = (const float*)d_in[2];
  const float* bF    = (const float*)d_in[3];
  const float* WihR  = (const float*)d_in[4];
  const float* WhhR  = (const float*)d_in[5];
  const float* bR    = (const float*)d_in[6];
  /* d_in[7] = Wih_d unused by reference decoder */
  const float* WhhD  = (const float*)d_in[8];
  const float* bD    = (const float*)d_in[9];
  const float* Wr_h  = (const float*)d_in[10];
  const float* br_h  = (const float*)d_in[11];
  const float* Wr_c  = (const float*)d_in[12];
  const float* br_c  = (const float*)d_in[13];
  const float* W1    = (const float*)d_in[14];
  const float* b1    = (const float*)d_in[15];
  const float* W2    = (const float*)d_in[16];
  const float* b2    = (const float*)d_in[17];
  const float* vt    = (const float*)d_in[18];
  const float* bvt   = (const float*)d_in[19];
  float* out = (float*)d_out;

  const size_t SBH = (size_t)S_ * B_ * H_;   // 8,388,608
  const size_t BH  = (size_t)B_ * H_;

  _Float16* hp = (_Float16*)d_ws;
  _Float16* hs_f  = hp;              hp += SBH;   // sentinel-filled
  _Float16* hs_r  = hp;              hp += SBH;   // sentinel-filled
  _Float16* hdec  = hp;              hp += SBH;   // sentinel-filled
  _Float16* pre1h = hp;              hp += SBH;
  _Float16* Qmh   = hp;              hp += SBH;
  _Float16* xh    = hp;              hp += (size_t)B_ * S_ * D_;
  _Float16* wihF  = hp;              hp += (size_t)4 * H_ * D_;
  _Float16* wihR  = hp;              hp += (size_t)4 * H_ * D_;
  _Float16* whhF  = hp;              hp += (size_t)4 * H_ * H_;
  _Float16* whhR  = hp;              hp += (size_t)4 * H_ * H_;
  _Float16* whhD  = hp;              hp += (size_t)4 * H_ * H_;
  _Float16* w1h   = hp;              hp += (size_t)H_ * H_;
  _Float16* w2h   = hp;              hp += (size_t)H_ * H_;
  float* fp  = (float*)hp;
  float* cF  = fp;                   fp += BH;
  float* cR  = fp;                   fp += BH;
  float* cD  = fp;                   fp += BH;
  float* hd0 = fp;                   fp += BH;

  // sentinel-fill the three h-exchange buffers
  fill_sent_k<<<2048, 256, 0, stream>>>((uint4*)hs_f, 3 * SBH / 8);

  // fp32 -> fp16 converts
  f2h_k<<<(B_ * S_ * D_ / 4 + 255) / 256, 256, 0, stream>>>(x, xh, B_ * S_ * D_ / 4);
  f2h_k<<<(4 * H_ * D_ / 4 + 255) / 256, 256, 0, stream>>>(WihF, wihF, 4 * H_ * D_ / 4);
  f2h_k<<<(4 * H_ * D_ / 4 + 255) / 256, 256, 0, stream>>>(WihR, wihR, 4 * H_ * D_ / 4);
  f2h_k<<<(4 * H_ * H_ / 4 + 255) / 256, 256, 0, stream>>>(WhhF, whhF, 4 * H_ * H_ / 4);
  f2h_k<<<(4 * H_ * H_ / 4 + 255) / 256, 256, 0, stream>>>(WhhR, whhR, 4 * H_ * H_ / 4);
  f2h_k<<<(4 * H_ * H_ / 4 + 255) / 256, 256, 0, stream>>>(WhhD, whhD, 4 * H_ * H_ / 4);
  f2h_k<<<(H_ * H_ / 4 + 255) / 256, 256, 0, stream>>>(W1, w1h, H_ * H_ / 4);
  f2h_k<<<(H_ * H_ / 4 + 255) / 256, 256, 0, stream>>>(W2, w2h, H_ * H_ / 4);

  // encoder: persistent MFMA, sentinel dataflow sync, coalesced publish
  enc_coop_k<<<512, 256, 0, stream>>>(xh, wihF, whhF, bF, wihR, whhR, bR,
                                      cF, cR, hs_f, hs_r);

  // decoder init
  gemm_cat_small_k<_Float16><<<dim3(1, 16), 256, 0, stream>>>(
      hs_f + (size_t)(S_ - 1) * BH, hs_r, Wr_h, br_h, hd0);
  gemm_cat_small_k<float><<<dim3(1, 16), 256, 0, stream>>>(cF, cR, Wr_c, br_c, cD);

  // pre1 = (hs_f + hs_r) @ W1^T + b1
  gemm_h_k<1><<<dim3(256, 8), 256, 0, stream>>>(hs_f, hs_r, w1h, b1, pre1h);

  // decoder: persistent MFMA, sentinel dataflow sync, coalesced publish
  dec_coop_k<<<512, 256, 0, stream>>>(hd0, cD, whhD, bD, hdec);

  // Q = Hdec @ W2^T + b2
  gemm_h_k<0><<<dim3(256, 8), 256, 0, stream>>>(hdec, nullptr, w2h, b2, Qmh);

  // attention
  attn_k<<<dim3(32, 32, 32), 256, 0, stream>>>(pre1h, Qmh, vt, bvt, out);
}

// Round 14
// 3955.578 us; speedup vs baseline: 1.5384x; 1.5384x over previous
//
#include <hip/hip_runtime.h>
#include <hip/hip_bf16.h>
#include <cstdint>
#include <cstddef>

#define B_ 32
#define S_ 512
#define D_ 256
#define H_ 512

typedef _Float16 h2 __attribute__((ext_vector_type(2)));
typedef _Float16 h4 __attribute__((ext_vector_type(4)));
typedef _Float16 h8 __attribute__((ext_vector_type(8)));
typedef float f32x4 __attribute__((ext_vector_type(4)));
typedef unsigned u32x4 __attribute__((ext_vector_type(4)));

__device__ __forceinline__ h2 H2(unsigned u) { return __builtin_bit_cast(h2, u); }
__device__ __forceinline__ unsigned U2(h2 v) { return __builtin_bit_cast(unsigned, v); }

#if __has_builtin(__builtin_amdgcn_fdot2)
__device__ __forceinline__ float dot2f(h2 a, h2 b, float c) {
  return __builtin_amdgcn_fdot2(a, b, c, false);
}
#else
__device__ __forceinline__ float dot2f(h2 a, h2 b, float c) {
  return c + (float)a.x * (float)b.x + (float)a.y * (float)b.y;
}
#endif

#if __has_builtin(__builtin_amdgcn_exp2f)
__device__ __forceinline__ float exp2_fast(float x) { return __builtin_amdgcn_exp2f(x); }
#else
__device__ __forceinline__ float exp2_fast(float x) { return exp2f(x); }
#endif
#if __has_builtin(__builtin_amdgcn_rcpf)
__device__ __forceinline__ float rcp_fast(float x) { return __builtin_amdgcn_rcpf(x); }
#else
__device__ __forceinline__ float rcp_fast(float x) { return 1.0f / x; }
#endif

__device__ __forceinline__ float sigm(float x) {
  return rcp_fast(1.0f + exp2_fast(-1.4426950408889634f * x));
}
__device__ __forceinline__ float tanh_fast(float x) {
  return 1.0f - 2.0f * rcp_fast(1.0f + exp2_fast(2.8853900817779268f * x));
}

// Coherent 16B load (bypass L1/L2, read L3). Caller MUST vm_drain() before use.
__device__ __forceinline__ uint4 coh_load16(const void* p) {
  u32x4 v;
  asm volatile("global_load_dwordx4 %0, %1, off sc0 sc1"
               : "=v"(v) : "v"(p) : "memory");
  return __builtin_bit_cast(uint4, v);
}
__device__ __forceinline__ void vm_drain() {
  asm volatile("s_waitcnt vmcnt(0)" ::: "memory");
}

// Sentinel = 0xFFFF per fp16 (a NaN). Legal h values are sigm*tanh in (-1,1)
// -> never NaN -> never 0xFFFF.
__device__ __forceinline__ bool valid16(uint4 v) {
  return ((v.x & 0xFFFFu) != 0xFFFFu) && ((v.x >> 16) != 0xFFFFu) &&
         ((v.y & 0xFFFFu) != 0xFFFFu) && ((v.y >> 16) != 0xFFFFu) &&
         ((v.z & 0xFFFFu) != 0xFFFFu) && ((v.z >> 16) != 0xFFFFu) &&
         ((v.w & 0xFFFFu) != 0xFFFFu) && ((v.w >> 16) != 0xFFFFu);
}

// h store: 2B write-through agent store (r11-proven form).
__device__ __forceinline__ void h_store(unsigned short* p, unsigned short v) {
  __hip_atomic_store(p, v, __ATOMIC_RELAXED, __HIP_MEMORY_SCOPE_AGENT);
}

// fill a region with the sentinel pattern (grid-stride, uint4 granularity)
__global__ __launch_bounds__(256) void fill_sent_k(uint4* __restrict__ dst, size_t n16) {
  uint4 s = {0xFFFFFFFFu, 0xFFFFFFFFu, 0xFFFFFFFFu, 0xFFFFFFFFu};
  size_t stride = (size_t)gridDim.x * 256;
  for (size_t i = (size_t)blockIdx.x * 256 + threadIdx.x; i < n16; i += stride)
    dst[i] = s;
}

// fp32 -> fp16 convert (4 elems/thread)
__global__ __launch_bounds__(256) void f2h_k(const float* __restrict__ src,
                                             _Float16* __restrict__ dst, int n4) {
  int i = blockIdx.x * 256 + threadIdx.x;
  if (i < n4) {
    float4 v = ((const float4*)src)[i];
    h4 o = {(_Float16)v.x, (_Float16)v.y, (_Float16)v.z, (_Float16)v.w};
    ((h4*)dst)[i] = o;
  }
}

// ---------------- persistent encoder: full-M MFMA + sentinel sync -----------
// 128 blocks = 4 groups (dir x 16-batch half) x 32 blocks of 16 h-cols.
// Wave = gate; MFMA 16x16x32 with M=16 real cols, N=16 real batches (no waste).
// Phases: stage x -> x-MFMA (hides h propagation) -> poll h -> h-MFMA -> cell.
__global__ __launch_bounds__(256, 1) void enc_coop_k(
    const _Float16* __restrict__ xh,
    const _Float16* __restrict__ WihF, const _Float16* __restrict__ WhhF, const float* __restrict__ bF,
    const _Float16* __restrict__ WihR, const _Float16* __restrict__ WhhR, const float* __restrict__ bR,
    float* __restrict__ cF, float* __restrict__ cR,
    _Float16* __restrict__ hsF, _Float16* __restrict__ hsR)
{
  __shared__ __align__(16) _Float16 cbuf[96][16][8];  // [k8][batch][8]
  __shared__ float zfin[4][16][17];                   // [gate][col][batch]
  __shared__ float cls[16][17];                       // c-state [col][batch]

  const int bid = blockIdx.x;
  const int group = bid >> 5;        // 0..3 = dir*2 + half
  const int dir = group >> 1;
  const int bh0 = (group & 1) << 4;  // batch base: 0 or 16
  const int jb = bid & 31;
  const int c0 = jb << 4;            // 16 h-cols per block
  const int tid = threadIdx.x;
  const int lane = tid & 63;
  const int wv = tid >> 6;           // wave = gate 0..3

  const _Float16* __restrict__ Wih = dir ? WihR : WihF;
  const _Float16* __restrict__ Whh = dir ? WhhR : WhhF;
  const float* __restrict__ bias = dir ? bR : bF;
  _Float16* __restrict__ hs = dir ? hsR : hsF;
  float* __restrict__ cOut = dir ? cR : cF;

  // A-fragments: lane holds W'[row = c0 + (lane&15), gate wv][k-octet lane>>4]
  h8 aw[24];
  {
    const int m = lane & 15, kg = lane >> 4;
    const int wrow = wv * H_ + c0 + m;
    const _Float16* wi = Wih + (size_t)wrow * D_;
    const _Float16* wh = Whh + (size_t)wrow * H_;
    #pragma unroll
    for (int tu = 0; tu < 24; ++tu) {
      int k = tu * 32 + kg * 8;
      aw[tu] = (k < 256) ? *(const h8*)(wi + k) : *(const h8*)(wh + (k - 256));
    }
  }

  const int cc = tid & 15, cb = tid >> 4;   // cell: col cc, batch cb (256 = 16x16)
  float bvg[4];
  #pragma unroll
  for (int g = 0; g < 4; ++g) bvg[g] = bias[g * H_ + c0 + cc];

  const char* cbase = (const char*)cbuf + (size_t)((lane >> 4) * 256 + (lane & 15) * 16);
  const int sn = tid & 15;            // staging batch
  const int xo = (tid >> 4) * 2;      // 2 x-octets
  const int ho = (tid >> 4) * 4;      // 4 h-octets
  __syncthreads();

  for (int t = 0; t < S_; ++t) {
    const int xi = dir ? (S_ - 1 - t) : t;

    {  // phase 1: stage x (cached loads)
      const _Float16* xp = xh + ((size_t)(bh0 + sn) * S_ + xi) * D_;
      uint4 v0 = *(const uint4*)(xp + xo * 8);
      uint4 v1 = *(const uint4*)(xp + xo * 8 + 8);
      *(uint4*)&cbuf[xo][sn][0] = v0;
      *(uint4*)&cbuf[xo + 1][sn][0] = v1;
    }
    __syncthreads();

    // phase 2: x-part MFMA (overlaps with producers' h-store propagation)
    f32x4 acc = {0.f, 0.f, 0.f, 0.f};
    #pragma unroll
    for (int tu = 0; tu < 8; ++tu) {
      h8 bf = *(const h8*)(cbase + tu * 1024);
      acc = __builtin_amdgcn_mfma_f32_16x16x32_f16(aw[tu], bf, acc, 0, 0, 0);
    }

    {  // phase 3: h_{t-1} via sentinel poll (or zeros at t=0)
      if (t == 0) {
        uint4 z = {0, 0, 0, 0};
        #pragma unroll
        for (int u = 0; u < 4; ++u) *(uint4*)&cbuf[32 + ho + u][sn][0] = z;
      } else {
        const int xip = dir ? xi + 1 : xi - 1;
        const _Float16* hbase = hs + ((size_t)xip * B_ + bh0 + sn) * H_;
        uint4 vs[4];
        unsigned pend = 0xF;
        do {
          #pragma unroll
          for (int u = 0; u < 4; ++u)
            if (pend & (1u << u)) vs[u] = coh_load16(hbase + (ho + u) * 8);
          vm_drain();
          #pragma unroll
          for (int u = 0; u < 4; ++u)
            if ((pend & (1u << u)) && valid16(vs[u])) pend &= ~(1u << u);
        } while (pend);
        #pragma unroll
        for (int u = 0; u < 4; ++u) *(uint4*)&cbuf[32 + ho + u][sn][0] = vs[u];
      }
    }
    __syncthreads();

    // phase 4: h-part MFMA
    #pragma unroll
    for (int tu = 8; tu < 24; ++tu) {
      h8 bf = *(const h8*)(cbase + tu * 1024);
      acc = __builtin_amdgcn_mfma_f32_16x16x32_f16(aw[tu], bf, acc, 0, 0, 0);
    }
    {  // D: col = lane&15 -> batch; row = (lane>>4)*4 + r -> block col
      const int mrow = (lane >> 4) * 4, n = lane & 15;
      #pragma unroll
      for (int r = 0; r < 4; ++r) zfin[wv][mrow + r][n] = acc[r];
    }
    __syncthreads();

    {  // cell: 16 cols x 16 batches = full block
      const float zi = zfin[0][cc][cb] + bvg[0];
      const float zf = zfin[1][cc][cb] + bvg[1];
      const float zg = zfin[2][cc][cb] + bvg[2];
      const float zo = zfin[3][cc][cb] + bvg[3];
      const float c_old = (t == 0) ? 0.f : cls[cc][cb];
      const float cn = sigm(zf) * c_old + sigm(zi) * tanh_fast(zg);
      const float hn = sigm(zo) * tanh_fast(cn);
      cls[cc][cb] = cn;
      _Float16 hh = (_Float16)hn;
      h_store((unsigned short*)(hs + ((size_t)xi * B_ + bh0 + cb) * H_ + c0 + cc),
              __builtin_bit_cast(unsigned short, hh));
      if (t == S_ - 1) cOut[(size_t)(bh0 + cb) * H_ + c0 + cc] = cn;
    }
    __syncthreads();   // protect zfin/cbuf reuse across iterations
  }
}

// ---------------- persistent decoder: full-M MFMA + sentinel sync -----------
// 64 blocks = 2 groups (16-batch halves) x 32 blocks of 16 h-cols. K = 512.
__global__ __launch_bounds__(256, 1) void dec_coop_k(
    const float* __restrict__ hd0, const float* __restrict__ cD0,
    const _Float16* __restrict__ Whh, const float* __restrict__ bias,
    _Float16* __restrict__ hdec)
{
  __shared__ __align__(16) _Float16 cbuf[64][16][8];
  __shared__ float zfin[4][16][17];
  __shared__ float cls[16][17];

  const int bid = blockIdx.x;
  const int group = bid >> 5;        // 0..1
  const int bh0 = group << 4;
  const int jb = bid & 31;
  const int c0 = jb << 4;
  const int tid = threadIdx.x;
  const int lane = tid & 63;
  const int wv = tid >> 6;

  h8 aw[16];
  {
    const int m = lane & 15, kg = lane >> 4;
    const _Float16* wh = Whh + (size_t)(wv * H_ + c0 + m) * H_;
    #pragma unroll
    for (int tu = 0; tu < 16; ++tu) aw[tu] = *(const h8*)(wh + tu * 32 + kg * 8);
  }

  const int cc = tid & 15, cb = tid >> 4;
  float bvg[4];
  #pragma unroll
  for (int g = 0; g < 4; ++g) bvg[g] = bias[g * H_ + c0 + cc];
  cls[cc][cb] = cD0[(size_t)(bh0 + cb) * H_ + c0 + cc];

  const char* cbase = (const char*)cbuf + (size_t)((lane >> 4) * 256 + (lane & 15) * 16);
  const int sn = tid & 15, ho = (tid >> 4) * 4;   // 4 octets per thread
  __syncthreads();

  for (int t = 0; t < S_; ++t) {
    {  // stage h_{t-1}: t=0 from hd0 (fp32), else sentinel-poll hdec[t-1]
      if (t == 0) {
        const float* src = hd0 + (size_t)(bh0 + sn) * H_;
        #pragma unroll
        for (int u = 0; u < 4; ++u) {
          float4 f0 = *(const float4*)(src + (ho + u) * 8);
          float4 f1 = *(const float4*)(src + (ho + u) * 8 + 4);
          h8 o = {(_Float16)f0.x, (_Float16)f0.y, (_Float16)f0.z, (_Float16)f0.w,
                  (_Float16)f1.x, (_Float16)f1.y, (_Float16)f1.z, (_Float16)f1.w};
          *(h8*)&cbuf[ho + u][sn][0] = o;
        }
      } else {
        const _Float16* src = hdec + ((size_t)(t - 1) * B_ + bh0 + sn) * H_;
        uint4 vs[4];
        unsigned pend = 0xF;
        do {
          #pragma unroll
          for (int u = 0; u < 4; ++u)
            if (pend & (1u << u)) vs[u] = coh_load16(src + (ho + u) * 8);
          vm_drain();
          #pragma unroll
          for (int u = 0; u < 4; ++u)
            if ((pend & (1u << u)) && valid16(vs[u])) pend &= ~(1u << u);
        } while (pend);
        #pragma unroll
        for (int u = 0; u < 4; ++u) *(uint4*)&cbuf[ho + u][sn][0] = vs[u];
      }
    }
    __syncthreads();

    f32x4 acc = {0.f, 0.f, 0.f, 0.f};
    #pragma unroll
    for (int tu = 0; tu < 16; ++tu) {
      h8 bf = *(const h8*)(cbase + tu * 1024);
      acc = __builtin_amdgcn_mfma_f32_16x16x32_f16(aw[tu], bf, acc, 0, 0, 0);
    }
    {
      const int mrow = (lane >> 4) * 4, n = lane & 15;
      #pragma unroll
      for (int r = 0; r < 4; ++r) zfin[wv][mrow + r][n] = acc[r];
    }
    __syncthreads();

    {  // cell: full block
      const float zi = zfin[0][cc][cb] + bvg[0];
      const float zf = zfin[1][cc][cb] + bvg[1];
      const float zg = zfin[2][cc][cb] + bvg[2];
      const float zo = zfin[3][cc][cb] + bvg[3];
      const float cn = sigm(zf) * cls[cc][cb] + sigm(zi) * tanh_fast(zg);
      const float hn = sigm(zo) * tanh_fast(cn);
      cls[cc][cb] = cn;
      _Float16 hh = (_Float16)hn;
      h_store((unsigned short*)(hdec + ((size_t)t * B_ + bh0 + cb) * H_ + c0 + cc),
              __builtin_bit_cast(unsigned short, hh));
    }
    __syncthreads();
  }
}

// ---------------- fp16 dot2 tiled GEMM: C[M,512] = op(A)@W^T + bias ----------
template <int MODE>
__global__ __launch_bounds__(256) void gemm_h_k(
    const _Float16* __restrict__ A1, const _Float16* __restrict__ A2,
    const _Float16* __restrict__ W, const float* __restrict__ bias,
    _Float16* __restrict__ C)
{
  __shared__ h2 As2[16][68];
  __shared__ h2 Bs2[16][68];
  const int tid = threadIdx.x;
  const int m0 = blockIdx.x * 64, n0 = blockIdx.y * 64;
  const int tn = tid & 15, tm = tid >> 4;
  float acc[4][4] = {};

  for (int kc = 0; kc < H_; kc += 32) {
    __syncthreads();
    {
      int mm = tid >> 2, q = tid & 3;
      uint4 a = *(const uint4*)(A1 + (size_t)(m0 + mm) * H_ + kc + q * 8);
      if (MODE == 1) {
        uint4 a2 = *(const uint4*)(A2 + (size_t)(m0 + mm) * H_ + kc + q * 8);
        a.x = U2(H2(a.x) + H2(a2.x)); a.y = U2(H2(a.y) + H2(a2.y));
        a.z = U2(H2(a.z) + H2(a2.z)); a.w = U2(H2(a.w) + H2(a2.w));
      }
      As2[q * 4 + 0][mm] = H2(a.x); As2[q * 4 + 1][mm] = H2(a.y);
      As2[q * 4 + 2][mm] = H2(a.z); As2[q * 4 + 3][mm] = H2(a.w);
      uint4 b = *(const uint4*)(W + (size_t)(n0 + mm) * H_ + kc + q * 8);
      Bs2[q * 4 + 0][mm] = H2(b.x); Bs2[q * 4 + 1][mm] = H2(b.y);
      Bs2[q * 4 + 2][mm] = H2(b.z); Bs2[q * 4 + 3][mm] = H2(b.w);
    }
    __syncthreads();
    #pragma unroll
    for (int k2 = 0; k2 < 16; ++k2) {
      uint4 au = *(const uint4*)&As2[k2][tm * 4];
      uint4 bu = *(const uint4*)&Bs2[k2][tn * 4];
      h2 a[4] = {H2(au.x), H2(au.y), H2(au.z), H2(au.w)};
      h2 b[4] = {H2(bu.x), H2(bu.y), H2(bu.z), H2(bu.w)};
      #pragma unroll
      for (int i = 0; i < 4; ++i)
        #pragma unroll
        for (int j = 0; j < 4; ++j)
          acc[i][j] = dot2f(a[i], b[j], acc[i][j]);
    }
  }
  float4 bl = *(const float4*)(bias + n0 + tn * 4);
  #pragma unroll
  for (int i = 0; i < 4; ++i) {
    h2 p0 = {(_Float16)(acc[i][0] + bl.x), (_Float16)(acc[i][1] + bl.y)};
    h2 p1 = {(_Float16)(acc[i][2] + bl.z), (_Float16)(acc[i][3] + bl.w)};
    uint2 st = {U2(p0), U2(p1)};
    *(uint2*)(C + (size_t)(m0 + tm * 4 + i) * H_ + n0 + tn * 4) = st;
  }
}

__device__ __forceinline__ float4 load4f(const float* p) { return *(const float4*)p; }
__device__ __forceinline__ float4 load4f(const _Float16* p) {
  uint2 u = *(const uint2*)p;
  h2 a = H2(u.x), b = H2(u.y);
  return make_float4((float)a.x, (float)a.y, (float)b.x, (float)b.y);
}

// small: C[32,512] = concat(A1,A2)@W^T + bias (K = 1024, halves of 512)
template <typename T>
__global__ __launch_bounds__(256) void gemm_cat_small_k(
    const T* __restrict__ A1, const T* __restrict__ A2,
    const float* __restrict__ W, const float* __restrict__ bias,
    float* __restrict__ C)
{
  const int tid = threadIdx.x;
  const int col = tid & 31;
  const int rg  = tid >> 5;
  const int n   = blockIdx.y * 32 + col;
  float acc[4] = {0, 0, 0, 0};
  #pragma unroll
  for (int pass = 0; pass < 2; ++pass) {
    const T* __restrict__ A = pass ? A2 : A1;
    const float4* __restrict__ w4 = (const float4*)(W + (size_t)n * 1024 + pass * 512);
    for (int k4 = 0; k4 < 128; ++k4) {
      float4 w = w4[k4];
      #pragma unroll
      for (int i = 0; i < 4; ++i) {
        int row = rg + (i << 3);
        float4 a = load4f(A + (size_t)row * H_ + k4 * 4);
        acc[i] += w.x * a.x + w.y * a.y + w.z * a.z + w.w * a.w;
      }
    }
  }
  const float bv = bias[n];
  #pragma unroll
  for (int i = 0; i < 4; ++i) {
    int row = rg + (i << 3);
    C[(size_t)row * H_ + n] = acc[i] + bv;
  }
}

// logits[b, t, s] = bvt + sum_h vt[h] * tanh(pre1[s,b,h] + Q[t,b,h])
__global__ __launch_bounds__(256) void attn_k(
    const _Float16* __restrict__ pre1, const _Float16* __restrict__ Qm,
    const float* __restrict__ vt, const float* __restrict__ bvt,
    float* __restrict__ out)
{
  __shared__ float sp[16][260];
  __shared__ float sq[16][260];
  __shared__ float sv[256];
  const int b = blockIdx.z, tbase = blockIdx.y << 4, sbase = blockIdx.x << 4;
  const int tid = threadIdx.x;
  const int so = tid & 15;
  const int to = tid >> 4;
  float acc = 0.f;

  for (int h0 = 0; h0 < H_; h0 += 256) {
    __syncthreads();
    {
      int i = tid >> 4, off = (tid & 15) * 16;
      uint4 q0 = *(const uint4*)(Qm + ((size_t)(tbase + i) * B_ + b) * H_ + h0 + off);
      uint4 q1 = *(const uint4*)(Qm + ((size_t)(tbase + i) * B_ + b) * H_ + h0 + off + 8);
      uint4 p0 = *(const uint4*)(pre1 + ((size_t)(sbase + i) * B_ + b) * H_ + h0 + off);
      uint4 p1 = *(const uint4*)(pre1 + ((size_t)(sbase + i) * B_ + b) * H_ + h0 + off + 8);
      const unsigned* qs = (const unsigned*)&q0;
      const unsigned* ps = (const unsigned*)&p0;
      #pragma unroll
      for (int u = 0; u < 4; ++u) {
        h2 qv = H2(qs[u]), pv = H2(ps[u]);
        sq[i][off + u * 2] = (float)qv.x; sq[i][off + u * 2 + 1] = (float)qv.y;
        sp[i][off + u * 2] = (float)pv.x; sp[i][off + u * 2 + 1] = (float)pv.y;
      }
      const unsigned* qs2 = (const unsigned*)&q1;
      const unsigned* ps2 = (const unsigned*)&p1;
      #pragma unroll
      for (int u = 0; u < 4; ++u) {
        h2 qv = H2(qs2[u]), pv = H2(ps2[u]);
        sq[i][off + 8 + u * 2] = (float)qv.x; sq[i][off + 8 + u * 2 + 1] = (float)qv.y;
        sp[i][off + 8 + u * 2] = (float)pv.x; sp[i][off + 8 + u * 2 + 1] = (float)pv.y;
      }
    }
    sv[tid] = vt[h0 + tid];
    __syncthreads();
    #pragma unroll 4
    for (int h = 0; h < 256; ++h)
      acc += sv[h] * tanh_fast(sp[so][h] + sq[to][h]);
  }
  out[((size_t)b * S_ + tbase + to) * S_ + sbase + so] = acc + bvt[0];
}

extern "C" void kernel_launch(void* const* d_in, const int* in_sizes, int n_in,
                              void* d_out, int out_size, void* d_ws, size_t ws_size,
                              hipStream_t stream)
{
  (void)in_sizes; (void)n_in; (void)out_size; (void)ws_size;
  const float* x     = (const float*)d_in[0];
  const float* WihF  = (const float*)d_in[1];
  const float* WhhF  = (const float*)d_in[2];
  const float* bF    = (const float*)d_in[3];
  const float* WihR  = (const float*)d_in[4];
  const float* WhhR  = (const float*)d_in[5];
  const float* bR    = (const float*)d_in[6];
  /* d_in[7] = Wih_d unused by reference decoder */
  const float* WhhD  = (const float*)d_in[8];
  const float* bD    = (const float*)d_in[9];
  const float* Wr_h  = (const float*)d_in[10];
  const float* br_h  = (const float*)d_in[11];
  const float* Wr_c  = (const float*)d_in[12];
  const float* br_c  = (const float*)d_in[13];
  const float* W1    = (const float*)d_in[14];
  const float* b1    = (const float*)d_in[15];
  const float* W2    = (const float*)d_in[16];
  const float* b2    = (const float*)d_in[17];
  const float* vt    = (const float*)d_in[18];
  const float* bvt   = (const float*)d_in[19];
  float* out = (float*)d_out;

  const size_t SBH = (size_t)S_ * B_ * H_;   // 8,388,608
  const size_t BH  = (size_t)B_ * H_;

  _Float16* hp = (_Float16*)d_ws;
  _Float16* hs_f  = hp;              hp += SBH;   // sentinel-filled
  _Float16* hs_r  = hp;              hp += SBH;   // sentinel-filled
  _Float16* hdec  = hp;              hp += SBH;   // sentinel-filled
  _Float16* pre1h = hp;              hp += SBH;
  _Float16* Qmh   = hp;              hp += SBH;
  _Float16* xh    = hp;              hp += (size_t)B_ * S_ * D_;
  _Float16* wihF  = hp;              hp += (size_t)4 * H_ * D_;
  _Float16* wihR  = hp;              hp += (size_t)4 * H_ * D_;
  _Float16* whhF  = hp;              hp += (size_t)4 * H_ * H_;
  _Float16* whhR  = hp;              hp += (size_t)4 * H_ * H_;
  _Float16* whhD  = hp;              hp += (size_t)4 * H_ * H_;
  _Float16* w1h   = hp;              hp += (size_t)H_ * H_;
  _Float16* w2h   = hp;              hp += (size_t)H_ * H_;
  float* fp  = (float*)hp;
  float* cF  = fp;                   fp += BH;
  float* cR  = fp;                   fp += BH;
  float* cD  = fp;                   fp += BH;
  float* hd0 = fp;                   fp += BH;

  // sentinel-fill the three h-exchange buffers
  fill_sent_k<<<2048, 256, 0, stream>>>((uint4*)hs_f, 3 * SBH / 8);

  // fp32 -> fp16 converts
  f2h_k<<<(B_ * S_ * D_ / 4 + 255) / 256, 256, 0, stream>>>(x, xh, B_ * S_ * D_ / 4);
  f2h_k<<<(4 * H_ * D_ / 4 + 255) / 256, 256, 0, stream>>>(WihF, wihF, 4 * H_ * D_ / 4);
  f2h_k<<<(4 * H_ * D_ / 4 + 255) / 256, 256, 0, stream>>>(WihR, wihR, 4 * H_ * D_ / 4);
  f2h_k<<<(4 * H_ * H_ / 4 + 255) / 256, 256, 0, stream>>>(WhhF, whhF, 4 * H_ * H_ / 4);
  f2h_k<<<(4 * H_ * H_ / 4 + 255) / 256, 256, 0, stream>>>(WhhR, whhR, 4 * H_ * H_ / 4);
  f2h_k<<<(4 * H_ * H_ / 4 + 255) / 256, 256, 0, stream>>>(WhhD, whhD, 4 * H_ * H_ / 4);
  f2h_k<<<(H_ * H_ / 4 + 255) / 256, 256, 0, stream>>>(W1, w1h, H_ * H_ / 4);
  f2h_k<<<(H_ * H_ / 4 + 255) / 256, 256, 0, stream>>>(W2, w2h, H_ * H_ / 4);

  // encoder: persistent full-M MFMA, sentinel dataflow sync (128 blocks)
  enc_coop_k<<<128, 256, 0, stream>>>(xh, wihF, whhF, bF, wihR, whhR, bR,
                                      cF, cR, hs_f, hs_r);

  // decoder init
  gemm_cat_small_k<_Float16><<<dim3(1, 16), 256, 0, stream>>>(
      hs_f + (size_t)(S_ - 1) * BH, hs_r, Wr_h, br_h, hd0);
  gemm_cat_small_k<float><<<dim3(1, 16), 256, 0, stream>>>(cF, cR, Wr_c, br_c, cD);

  // pre1 = (hs_f + hs_r) @ W1^T + b1
  gemm_h_k<1><<<dim3(256, 8), 256, 0, stream>>>(hs_f, hs_r, w1h, b1, pre1h);

  // decoder: persistent full-M MFMA, sentinel dataflow sync (64 blocks)
  dec_coop_k<<<64, 256, 0, stream>>>(hd0, cD, whhD, bD, hdec);

  // Q = Hdec @ W2^T + b2
  gemm_h_k<0><<<dim3(256, 8), 256, 0, stream>>>(hdec, nullptr, w2h, b2, Qmh);

  // attention
  attn_k<<<dim3(32, 32, 32), 256, 0, stream>>>(pre1h, Qmh, vt, bvt, out);
}

// Round 15
// 3479.583 us; speedup vs baseline: 1.7488x; 1.1368x over previous
//
#include <hip/hip_runtime.h>
#include <hip/hip_bf16.h>
#include <cstdint>
#include <cstddef>

#define B_ 32
#define S_ 512
#define D_ 256
#define H_ 512

typedef _Float16 h2 __attribute__((ext_vector_type(2)));
typedef _Float16 h4 __attribute__((ext_vector_type(4)));
typedef _Float16 h8 __attribute__((ext_vector_type(8)));
typedef float f32x4 __attribute__((ext_vector_type(4)));
typedef unsigned u32x4 __attribute__((ext_vector_type(4)));

__device__ __forceinline__ h2 H2(unsigned u) { return __builtin_bit_cast(h2, u); }
__device__ __forceinline__ unsigned U2(h2 v) { return __builtin_bit_cast(unsigned, v); }

#if __has_builtin(__builtin_amdgcn_exp2f)
__device__ __forceinline__ float exp2_fast(float x) { return __builtin_amdgcn_exp2f(x); }
#else
__device__ __forceinline__ float exp2_fast(float x) { return exp2f(x); }
#endif
#if __has_builtin(__builtin_amdgcn_rcpf)
__device__ __forceinline__ float rcp_fast(float x) { return __builtin_amdgcn_rcpf(x); }
#else
__device__ __forceinline__ float rcp_fast(float x) { return 1.0f / x; }
#endif

__device__ __forceinline__ float sigm(float x) {
  return rcp_fast(1.0f + exp2_fast(-1.4426950408889634f * x));
}
__device__ __forceinline__ float tanh_fast(float x) {
  return 1.0f - 2.0f * rcp_fast(1.0f + exp2_fast(2.8853900817779268f * x));
}

// Coherent 16B load (bypass L1/L2, read L3). Caller MUST vm_drain() before use.
__device__ __forceinline__ uint4 coh_load16(const void* p) {
  u32x4 v;
  asm volatile("global_load_dwordx4 %0, %1, off sc0 sc1"
               : "=v"(v) : "v"(p) : "memory");
  return __builtin_bit_cast(uint4, v);
}
__device__ __forceinline__ void vm_drain() {
  asm volatile("s_waitcnt vmcnt(0)" ::: "memory");
}

// Sentinel = 0xFFFF per fp16 (a NaN). Legal h values are sigm*tanh in (-1,1)
// -> never NaN -> never 0xFFFF.
__device__ __forceinline__ bool valid16(uint4 v) {
  return ((v.x & 0xFFFFu) != 0xFFFFu) && ((v.x >> 16) != 0xFFFFu) &&
         ((v.y & 0xFFFFu) != 0xFFFFu) && ((v.y >> 16) != 0xFFFFu) &&
         ((v.z & 0xFFFFu) != 0xFFFFu) && ((v.z >> 16) != 0xFFFFu) &&
         ((v.w & 0xFFFFu) != 0xFFFFu) && ((v.w >> 16) != 0xFFFFu);
}

// h store: 2B write-through agent store (r11-proven form).
__device__ __forceinline__ void h_store(unsigned short* p, unsigned short v) {
  __hip_atomic_store(p, v, __ATOMIC_RELAXED, __HIP_MEMORY_SCOPE_AGENT);
}

// fill a region with the sentinel pattern (grid-stride, uint4 granularity)
__global__ __launch_bounds__(256) void fill_sent_k(uint4* __restrict__ dst, size_t n16) {
  uint4 s = {0xFFFFFFFFu, 0xFFFFFFFFu, 0xFFFFFFFFu, 0xFFFFFFFFu};
  size_t stride = (size_t)gridDim.x * 256;
  for (size_t i = (size_t)blockIdx.x * 256 + threadIdx.x; i < n16; i += stride)
    dst[i] = s;
}

// fp32 -> fp16 convert (4 elems/thread)
__global__ __launch_bounds__(256) void f2h_k(const float* __restrict__ src,
                                             _Float16* __restrict__ dst, int n4) {
  int i = blockIdx.x * 256 + threadIdx.x;
  if (i < n4) {
    float4 v = ((const float4*)src)[i];
    h4 o = {(_Float16)v.x, (_Float16)v.y, (_Float16)v.z, (_Float16)v.w};
    ((h4*)dst)[i] = o;
  }
}

// ---------------- persistent encoder: full-M MFMA + sentinel sync -----------
// 128 blocks = 4 groups (dir x 16-batch half) x 32 blocks of 16 h-cols.
__global__ __launch_bounds__(256, 1) void enc_coop_k(
    const _Float16* __restrict__ xh,
    const _Float16* __restrict__ WihF, const _Float16* __restrict__ WhhF, const float* __restrict__ bF,
    const _Float16* __restrict__ WihR, const _Float16* __restrict__ WhhR, const float* __restrict__ bR,
    float* __restrict__ cF, float* __restrict__ cR,
    _Float16* __restrict__ hsF, _Float16* __restrict__ hsR)
{
  __shared__ __align__(16) _Float16 cbuf[96][16][8];  // [k8][batch][8]
  __shared__ float zfin[4][16][17];                   // [gate][col][batch]
  __shared__ float cls[16][17];                       // c-state [col][batch]

  const int bid = blockIdx.x;
  const int group = bid >> 5;        // 0..3 = dir*2 + half
  const int dir = group >> 1;
  const int bh0 = (group & 1) << 4;  // batch base: 0 or 16
  const int jb = bid & 31;
  const int c0 = jb << 4;            // 16 h-cols per block
  const int tid = threadIdx.x;
  const int lane = tid & 63;
  const int wv = tid >> 6;           // wave = gate 0..3

  const _Float16* __restrict__ Wih = dir ? WihR : WihF;
  const _Float16* __restrict__ Whh = dir ? WhhR : WhhF;
  const float* __restrict__ bias = dir ? bR : bF;
  _Float16* __restrict__ hs = dir ? hsR : hsF;
  float* __restrict__ cOut = dir ? cR : cF;

  h8 aw[24];
  {
    const int m = lane & 15, kg = lane >> 4;
    const int wrow = wv * H_ + c0 + m;
    const _Float16* wi = Wih + (size_t)wrow * D_;
    const _Float16* wh = Whh + (size_t)wrow * H_;
    #pragma unroll
    for (int tu = 0; tu < 24; ++tu) {
      int k = tu * 32 + kg * 8;
      aw[tu] = (k < 256) ? *(const h8*)(wi + k) : *(const h8*)(wh + (k - 256));
    }
  }

  const int cc = tid & 15, cb = tid >> 4;
  float bvg[4];
  #pragma unroll
  for (int g = 0; g < 4; ++g) bvg[g] = bias[g * H_ + c0 + cc];

  const char* cbase = (const char*)cbuf + (size_t)((lane >> 4) * 256 + (lane & 15) * 16);
  const int sn = tid & 15;
  const int xo = (tid >> 4) * 2;
  const int ho = (tid >> 4) * 4;
  __syncthreads();

  for (int t = 0; t < S_; ++t) {
    const int xi = dir ? (S_ - 1 - t) : t;

    {  // phase 1: stage x (cached loads)
      const _Float16* xp = xh + ((size_t)(bh0 + sn) * S_ + xi) * D_;
      uint4 v0 = *(const uint4*)(xp + xo * 8);
      uint4 v1 = *(const uint4*)(xp + xo * 8 + 8);
      *(uint4*)&cbuf[xo][sn][0] = v0;
      *(uint4*)&cbuf[xo + 1][sn][0] = v1;
    }
    __syncthreads();

    f32x4 acc = {0.f, 0.f, 0.f, 0.f};
    #pragma unroll
    for (int tu = 0; tu < 8; ++tu) {
      h8 bf = *(const h8*)(cbase + tu * 1024);
      acc = __builtin_amdgcn_mfma_f32_16x16x32_f16(aw[tu], bf, acc, 0, 0, 0);
    }

    {  // phase 3: h_{t-1} via sentinel poll (or zeros at t=0)
      if (t == 0) {
        uint4 z = {0, 0, 0, 0};
        #pragma unroll
        for (int u = 0; u < 4; ++u) *(uint4*)&cbuf[32 + ho + u][sn][0] = z;
      } else {
        const int xip = dir ? xi + 1 : xi - 1;
        const _Float16* hbase = hs + ((size_t)xip * B_ + bh0 + sn) * H_;
        uint4 vs[4];
        unsigned pend = 0xF;
        do {
          #pragma unroll
          for (int u = 0; u < 4; ++u)
            if (pend & (1u << u)) vs[u] = coh_load16(hbase + (ho + u) * 8);
          vm_drain();
          #pragma unroll
          for (int u = 0; u < 4; ++u)
            if ((pend & (1u << u)) && valid16(vs[u])) pend &= ~(1u << u);
        } while (pend);
        #pragma unroll
        for (int u = 0; u < 4; ++u) *(uint4*)&cbuf[32 + ho + u][sn][0] = vs[u];
      }
    }
    __syncthreads();

    #pragma unroll
    for (int tu = 8; tu < 24; ++tu) {
      h8 bf = *(const h8*)(cbase + tu * 1024);
      acc = __builtin_amdgcn_mfma_f32_16x16x32_f16(aw[tu], bf, acc, 0, 0, 0);
    }
    {
      const int mrow = (lane >> 4) * 4, n = lane & 15;
      #pragma unroll
      for (int r = 0; r < 4; ++r) zfin[wv][mrow + r][n] = acc[r];
    }
    __syncthreads();

    {  // cell: 16 cols x 16 batches
      const float zi = zfin[0][cc][cb] + bvg[0];
      const float zf = zfin[1][cc][cb] + bvg[1];
      const float zg = zfin[2][cc][cb] + bvg[2];
      const float zo = zfin[3][cc][cb] + bvg[3];
      const float c_old = (t == 0) ? 0.f : cls[cc][cb];
      const float cn = sigm(zf) * c_old + sigm(zi) * tanh_fast(zg);
      const float hn = sigm(zo) * tanh_fast(cn);
      cls[cc][cb] = cn;
      _Float16 hh = (_Float16)hn;
      h_store((unsigned short*)(hs + ((size_t)xi * B_ + bh0 + cb) * H_ + c0 + cc),
              __builtin_bit_cast(unsigned short, hh));
      if (t == S_ - 1) cOut[(size_t)(bh0 + cb) * H_ + c0 + cc] = cn;
    }
    __syncthreads();
  }
}

// ---------------- persistent decoder: full-M MFMA + sentinel sync -----------
// 64 blocks = 2 groups (16-batch halves) x 32 blocks of 16 h-cols. K = 512.
__global__ __launch_bounds__(256, 1) void dec_coop_k(
    const float* __restrict__ hd0, const float* __restrict__ cD0,
    const _Float16* __restrict__ Whh, const float* __restrict__ bias,
    _Float16* __restrict__ hdec)
{
  __shared__ __align__(16) _Float16 cbuf[64][16][8];
  __shared__ float zfin[4][16][17];
  __shared__ float cls[16][17];

  const int bid = blockIdx.x;
  const int group = bid >> 5;
  const int bh0 = group << 4;
  const int jb = bid & 31;
  const int c0 = jb << 4;
  const int tid = threadIdx.x;
  const int lane = tid & 63;
  const int wv = tid >> 6;

  h8 aw[16];
  {
    const int m = lane & 15, kg = lane >> 4;
    const _Float16* wh = Whh + (size_t)(wv * H_ + c0 + m) * H_;
    #pragma unroll
    for (int tu = 0; tu < 16; ++tu) aw[tu] = *(const h8*)(wh + tu * 32 + kg * 8);
  }

  const int cc = tid & 15, cb = tid >> 4;
  float bvg[4];
  #pragma unroll
  for (int g = 0; g < 4; ++g) bvg[g] = bias[g * H_ + c0 + cc];
  cls[cc][cb] = cD0[(size_t)(bh0 + cb) * H_ + c0 + cc];

  const char* cbase = (const char*)cbuf + (size_t)((lane >> 4) * 256 + (lane & 15) * 16);
  const int sn = tid & 15, ho = (tid >> 4) * 4;
  __syncthreads();

  for (int t = 0; t < S_; ++t) {
    {
      if (t == 0) {
        const float* src = hd0 + (size_t)(bh0 + sn) * H_;
        #pragma unroll
        for (int u = 0; u < 4; ++u) {
          float4 f0 = *(const float4*)(src + (ho + u) * 8);
          float4 f1 = *(const float4*)(src + (ho + u) * 8 + 4);
          h8 o = {(_Float16)f0.x, (_Float16)f0.y, (_Float16)f0.z, (_Float16)f0.w,
                  (_Float16)f1.x, (_Float16)f1.y, (_Float16)f1.z, (_Float16)f1.w};
          *(h8*)&cbuf[ho + u][sn][0] = o;
        }
      } else {
        const _Float16* src = hdec + ((size_t)(t - 1) * B_ + bh0 + sn) * H_;
        uint4 vs[4];
        unsigned pend = 0xF;
        do {
          #pragma unroll
          for (int u = 0; u < 4; ++u)
            if (pend & (1u << u)) vs[u] = coh_load16(src + (ho + u) * 8);
          vm_drain();
          #pragma unroll
          for (int u = 0; u < 4; ++u)
            if ((pend & (1u << u)) && valid16(vs[u])) pend &= ~(1u << u);
        } while (pend);
        #pragma unroll
        for (int u = 0; u < 4; ++u) *(uint4*)&cbuf[ho + u][sn][0] = vs[u];
      }
    }
    __syncthreads();

    f32x4 acc = {0.f, 0.f, 0.f, 0.f};
    #pragma unroll
    for (int tu = 0; tu < 16; ++tu) {
      h8 bf = *(const h8*)(cbase + tu * 1024);
      acc = __builtin_amdgcn_mfma_f32_16x16x32_f16(aw[tu], bf, acc, 0, 0, 0);
    }
    {
      const int mrow = (lane >> 4) * 4, n = lane & 15;
      #pragma unroll
      for (int r = 0; r < 4; ++r) zfin[wv][mrow + r][n] = acc[r];
    }
    __syncthreads();

    {
      const float zi = zfin[0][cc][cb] + bvg[0];
      const float zf = zfin[1][cc][cb] + bvg[1];
      const float zg = zfin[2][cc][cb] + bvg[2];
      const float zo = zfin[3][cc][cb] + bvg[3];
      const float cn = sigm(zf) * cls[cc][cb] + sigm(zi) * tanh_fast(zg);
      const float hn = sigm(zo) * tanh_fast(cn);
      cls[cc][cb] = cn;
      _Float16 hh = (_Float16)hn;
      h_store((unsigned short*)(hdec + ((size_t)t * B_ + bh0 + cb) * H_ + c0 + cc),
              __builtin_bit_cast(unsigned short, hh));
    }
    __syncthreads();
  }
}

// ---------------- MFMA tiled GEMM: C[M,512] = op(A1,A2) @ W^T + bias --------
// 64x64 tile, K-chunk 32, 4 waves each own an m-quadrant, loop 4 n-tiles.
// LDS [k8][row][8] with +2-row pad -> conflict-free b128 frag reads/writes.
template <int MODE>
__global__ __launch_bounds__(256) void gemm_mfma_k(
    const _Float16* __restrict__ A1, const _Float16* __restrict__ A2,
    const _Float16* __restrict__ W, const float* __restrict__ bias,
    _Float16* __restrict__ C)
{
  __shared__ __align__(16) _Float16 Abuf[4][66][8];
  __shared__ __align__(16) _Float16 Bbuf[4][66][8];
  const int tid = threadIdx.x;
  const int m0 = blockIdx.x * 64, n0 = blockIdx.y * 64;
  const int lane = tid & 63, wv = tid >> 6;
  const int sr = tid >> 2, sk = tid & 3;   // staging: row, k-octet
  f32x4 acc[4] = {{0.f,0.f,0.f,0.f},{0.f,0.f,0.f,0.f},
                  {0.f,0.f,0.f,0.f},{0.f,0.f,0.f,0.f}};

  for (int kc = 0; kc < H_; kc += 32) {
    __syncthreads();
    {
      uint4 a = *(const uint4*)(A1 + (size_t)(m0 + sr) * H_ + kc + sk * 8);
      if (MODE == 1) {
        uint4 a2 = *(const uint4*)(A2 + (size_t)(m0 + sr) * H_ + kc + sk * 8);
        a.x = U2(H2(a.x) + H2(a2.x)); a.y = U2(H2(a.y) + H2(a2.y));
        a.z = U2(H2(a.z) + H2(a2.z)); a.w = U2(H2(a.w) + H2(a2.w));
      }
      *(uint4*)&Abuf[sk][sr][0] = a;
      uint4 b = *(const uint4*)(W + (size_t)(n0 + sr) * H_ + kc + sk * 8);
      *(uint4*)&Bbuf[sk][sr][0] = b;
    }
    __syncthreads();
    const int fr = lane & 15, kg = lane >> 4;
    h8 af = *(const h8*)&Abuf[kg][wv * 16 + fr][0];
    #pragma unroll
    for (int nt = 0; nt < 4; ++nt) {
      h8 bf = *(const h8*)&Bbuf[kg][nt * 16 + fr][0];
      acc[nt] = __builtin_amdgcn_mfma_f32_16x16x32_f16(af, bf, acc[nt], 0, 0, 0);
    }
  }
  // D layout: col(lane&15) = B-row (n), row((lane>>4)*4+r) = A-row (m)
  const int fr = lane & 15, fq = lane >> 4;
  #pragma unroll
  for (int nt = 0; nt < 4; ++nt) {
    const int n = n0 + nt * 16 + fr;
    const float bv = bias[n];
    #pragma unroll
    for (int r = 0; r < 4; ++r) {
      const int m = m0 + wv * 16 + fq * 4 + r;
      C[(size_t)m * H_ + n] = (_Float16)(acc[nt][r] + bv);
    }
  }
}

__device__ __forceinline__ float4 load4f(const float* p) { return *(const float4*)p; }
__device__ __forceinline__ float4 load4f(const _Float16* p) {
  uint2 u = *(const uint2*)p;
  h2 a = H2(u.x), b = H2(u.y);
  return make_float4((float)a.x, (float)a.y, (float)b.x, (float)b.y);
}

// small: C[32,512] = concat(A1,A2)@W^T + bias (K = 1024, halves of 512)
template <typename T>
__global__ __launch_bounds__(256) void gemm_cat_small_k(
    const T* __restrict__ A1, const T* __restrict__ A2,
    const float* __restrict__ W, const float* __restrict__ bias,
    float* __restrict__ C)
{
  const int tid = threadIdx.x;
  const int col = tid & 31;
  const int rg  = tid >> 5;
  const int n   = blockIdx.y * 32 + col;
  float acc[4] = {0, 0, 0, 0};
  #pragma unroll
  for (int pass = 0; pass < 2; ++pass) {
    const T* __restrict__ A = pass ? A2 : A1;
    const float4* __restrict__ w4 = (const float4*)(W + (size_t)n * 1024 + pass * 512);
    for (int k4 = 0; k4 < 128; ++k4) {
      float4 w = w4[k4];
      #pragma unroll
      for (int i = 0; i < 4; ++i) {
        int row = rg + (i << 3);
        float4 a = load4f(A + (size_t)row * H_ + k4 * 4);
        acc[i] += w.x * a.x + w.y * a.y + w.z * a.z + w.w * a.w;
      }
    }
  }
  const float bv = bias[n];
  #pragma unroll
  for (int i = 0; i < 4; ++i) {
    int row = rg + (i << 3);
    C[(size_t)row * H_ + n] = acc[i] + bv;
  }
}

__global__ __launch_bounds__(256) void sumv_k(const float* __restrict__ vt,
                                              float* __restrict__ o) {
  __shared__ float sh[4];
  float v = vt[threadIdx.x] + vt[threadIdx.x + 256];
  #pragma unroll
  for (int d = 32; d; d >>= 1) v += __shfl_down(v, d, 64);
  if ((threadIdx.x & 63) == 0) sh[threadIdx.x >> 6] = v;
  __syncthreads();
  if (threadIdx.x == 0) o[0] = sh[0] + sh[1] + sh[2] + sh[3];
}

// logits[b,t,s] = (sumv + bvt) - 2 * sum_h v[h] * rcp(Ep[s,h]*Eq[t,h] + 1)
// Ep = exp2(c*pre1), Eq = exp2(c*q), c = 2*log2(e). |p|,|q| ~ O(1) so
// exp2 args ~ +-10 << clamp +-60 (never fires); product <= 2^120 safe in fp32.
#define KT_ 2.8853900817779268f
__global__ __launch_bounds__(256) void attn_k(
    const _Float16* __restrict__ pre1, const _Float16* __restrict__ Qm,
    const float* __restrict__ vt, const float* __restrict__ bvt,
    const float* __restrict__ sumv, float* __restrict__ out)
{
  __shared__ float sp[16][260];
  __shared__ float sq[16][260];
  __shared__ float sv[256];
  const int b = blockIdx.z, tbase = blockIdx.y << 4, sbase = blockIdx.x << 4;
  const int tid = threadIdx.x;
  const int so = tid & 15, to = tid >> 4;
  float acc = 0.f;
  const float cfin = sumv[0] + bvt[0];

  for (int h0 = 0; h0 < H_; h0 += 256) {
    __syncthreads();
    {
      int i = tid >> 4, off = (tid & 15) * 16;
      const _Float16* qp = Qm + ((size_t)(tbase + i) * B_ + b) * H_ + h0 + off;
      const _Float16* pp = pre1 + ((size_t)(sbase + i) * B_ + b) * H_ + h0 + off;
      h8 q0 = *(const h8*)qp, q1 = *(const h8*)(qp + 8);
      h8 p0 = *(const h8*)pp, p1 = *(const h8*)(pp + 8);
      #pragma unroll
      for (int j = 0; j < 8; ++j) {
        sq[i][off + j]     = exp2_fast(fminf(fmaxf(KT_ * (float)q0[j], -60.f), 60.f));
        sq[i][off + 8 + j] = exp2_fast(fminf(fmaxf(KT_ * (float)q1[j], -60.f), 60.f));
        sp[i][off + j]     = exp2_fast(fminf(fmaxf(KT_ * (float)p0[j], -60.f), 60.f));
        sp[i][off + 8 + j] = exp2_fast(fminf(fmaxf(KT_ * (float)p1[j], -60.f), 60.f));
      }
    }
    sv[tid] = vt[h0 + tid];
    __syncthreads();
    #pragma unroll 4
    for (int h = 0; h < 256; ++h)
      acc = fmaf(sv[h], rcp_fast(fmaf(sp[so][h], sq[to][h], 1.0f)), acc);
  }
  out[((size_t)b * S_ + tbase + to) * S_ + sbase + so] = cfin - 2.f * acc;
}

extern "C" void kernel_launch(void* const* d_in, const int* in_sizes, int n_in,
                              void* d_out, int out_size, void* d_ws, size_t ws_size,
                              hipStream_t stream)
{
  (void)in_sizes; (void)n_in; (void)out_size; (void)ws_size;
  const float* x     = (const float*)d_in[0];
  const float* WihF  = (const float*)d_in[1];
  const float* WhhF  = (const float*)d_in[2];
  const float* bF    = (const float*)d_in[3];
  const float* WihR  = (const float*)d_in[4];
  const float* WhhR  = (const float*)d_in[5];
  const float* bR    = (const float*)d_in[6];
  /* d_in[7] = Wih_d unused by reference decoder */
  const float* WhhD  = (const float*)d_in[8];
  const float* bD    = (const float*)d_in[9];
  const float* Wr_h  = (const float*)d_in[10];
  const float* br_h  = (const float*)d_in[11];
  const float* Wr_c  = (const float*)d_in[12];
  const float* br_c  = (const float*)d_in[13];
  const float* W1    = (const float*)d_in[14];
  const float* b1    = (const float*)d_in[15];
  const float* W2    = (const float*)d_in[16];
  const float* b2    = (const float*)d_in[17];
  const float* vt    = (const float*)d_in[18];
  const float* bvt   = (const float*)d_in[19];
  float* out = (float*)d_out;

  const size_t SBH = (size_t)S_ * B_ * H_;   // 8,388,608
  const size_t BH  = (size_t)B_ * H_;

  _Float16* hp = (_Float16*)d_ws;
  _Float16* hs_f  = hp;              hp += SBH;   // sentinel-filled
  _Float16* hs_r  = hp;              hp += SBH;   // sentinel-filled
  _Float16* hdec  = hp;              hp += SBH;   // sentinel-filled
  _Float16* pre1h = hp;              hp += SBH;
  _Float16* Qmh   = hp;              hp += SBH;
  _Float16* xh    = hp;              hp += (size_t)B_ * S_ * D_;
  _Float16* wihF  = hp;              hp += (size_t)4 * H_ * D_;
  _Float16* wihR  = hp;              hp += (size_t)4 * H_ * D_;
  _Float16* whhF  = hp;              hp += (size_t)4 * H_ * H_;
  _Float16* whhR  = hp;              hp += (size_t)4 * H_ * H_;
  _Float16* whhD  = hp;              hp += (size_t)4 * H_ * H_;
  _Float16* w1h   = hp;              hp += (size_t)H_ * H_;
  _Float16* w2h   = hp;              hp += (size_t)H_ * H_;
  float* fp  = (float*)hp;
  float* cF  = fp;                   fp += BH;
  float* cR  = fp;                   fp += BH;
  float* cD  = fp;                   fp += BH;
  float* hd0 = fp;                   fp += BH;
  float* sumv = fp;

  // sentinel-fill the three h-exchange buffers
  fill_sent_k<<<2048, 256, 0, stream>>>((uint4*)hs_f, 3 * SBH / 8);

  // fp32 -> fp16 converts
  f2h_k<<<(B_ * S_ * D_ / 4 + 255) / 256, 256, 0, stream>>>(x, xh, B_ * S_ * D_ / 4);
  f2h_k<<<(4 * H_ * D_ / 4 + 255) / 256, 256, 0, stream>>>(WihF, wihF, 4 * H_ * D_ / 4);
  f2h_k<<<(4 * H_ * D_ / 4 + 255) / 256, 256, 0, stream>>>(WihR, wihR, 4 * H_ * D_ / 4);
  f2h_k<<<(4 * H_ * H_ / 4 + 255) / 256, 256, 0, stream>>>(WhhF, whhF, 4 * H_ * H_ / 4);
  f2h_k<<<(4 * H_ * H_ / 4 + 255) / 256, 256, 0, stream>>>(WhhR, whhR, 4 * H_ * H_ / 4);
  f2h_k<<<(4 * H_ * H_ / 4 + 255) / 256, 256, 0, stream>>>(WhhD, whhD, 4 * H_ * H_ / 4);
  f2h_k<<<(H_ * H_ / 4 + 255) / 256, 256, 0, stream>>>(W1, w1h, H_ * H_ / 4);
  f2h_k<<<(H_ * H_ / 4 + 255) / 256, 256, 0, stream>>>(W2, w2h, H_ * H_ / 4);
  sumv_k<<<1, 256, 0, stream>>>(vt, sumv);

  // encoder: persistent full-M MFMA, sentinel dataflow sync (128 blocks)
  enc_coop_k<<<128, 256, 0, stream>>>(xh, wihF, whhF, bF, wihR, whhR, bR,
                                      cF, cR, hs_f, hs_r);

  // decoder init
  gemm_cat_small_k<_Float16><<<dim3(1, 16), 256, 0, stream>>>(
      hs_f + (size_t)(S_ - 1) * BH, hs_r, Wr_h, br_h, hd0);
  gemm_cat_small_k<float><<<dim3(1, 16), 256, 0, stream>>>(cF, cR, Wr_c, br_c, cD);

  // pre1 = (hs_f + hs_r) @ W1^T + b1   (MFMA)
  gemm_mfma_k<1><<<dim3(256, 8), 256, 0, stream>>>(hs_f, hs_r, w1h, b1, pre1h);

  // decoder: persistent full-M MFMA, sentinel dataflow sync (64 blocks)
  dec_coop_k<<<64, 256, 0, stream>>>(hd0, cD, whhD, bD, hdec);

  // Q = Hdec @ W2^T + b2   (MFMA)
  gemm_mfma_k<0><<<dim3(256, 8), 256, 0, stream>>>(hdec, nullptr, w2h, b2, Qmh);

  // attention (exp-product tanh)
  attn_k<<<dim3(32, 32, 32), 256, 0, stream>>>(pre1h, Qmh, vt, bvt, sumv, out);
}

// Round 17
// 3374.011 us; speedup vs baseline: 1.8035x; 1.0313x over previous
//
#include <hip/hip_runtime.h>
#include <hip/hip_bf16.h>
#include <cstdint>
#include <cstddef>

#define B_ 32
#define S_ 512
#define D_ 256
#define H_ 512

typedef _Float16 h2 __attribute__((ext_vector_type(2)));
typedef _Float16 h4 __attribute__((ext_vector_type(4)));
typedef _Float16 h8 __attribute__((ext_vector_type(8)));
typedef float f32x4 __attribute__((ext_vector_type(4)));
typedef unsigned u32x4 __attribute__((ext_vector_type(4)));

__device__ __forceinline__ h2 H2(unsigned u) { return __builtin_bit_cast(h2, u); }
__device__ __forceinline__ unsigned U2(h2 v) { return __builtin_bit_cast(unsigned, v); }

#if __has_builtin(__builtin_amdgcn_exp2f)
__device__ __forceinline__ float exp2_fast(float x) { return __builtin_amdgcn_exp2f(x); }
#else
__device__ __forceinline__ float exp2_fast(float x) { return exp2f(x); }
#endif
#if __has_builtin(__builtin_amdgcn_rcpf)
__device__ __forceinline__ float rcp_fast(float x) { return __builtin_amdgcn_rcpf(x); }
#else
__device__ __forceinline__ float rcp_fast(float x) { return 1.0f / x; }
#endif

__device__ __forceinline__ float sigm(float x) {
  return rcp_fast(1.0f + exp2_fast(-1.4426950408889634f * x));
}
__device__ __forceinline__ float tanh_fast(float x) {
  return 1.0f - 2.0f * rcp_fast(1.0f + exp2_fast(2.8853900817779268f * x));
}

// Coherent 16B load (bypass L1/L2, read L3). MUST be drained (vm_drain)
// IMMEDIATELY after issue, before any other code touches the outputs:
// the compiler does not model vmcnt for inline-asm outputs (r16 lesson).
__device__ __forceinline__ uint4 coh_load16(const void* p) {
  u32x4 v;
  asm volatile("global_load_dwordx4 %0, %1, off sc0 sc1"
               : "=v"(v) : "v"(p) : "memory");
  return __builtin_bit_cast(uint4, v);
}
__device__ __forceinline__ void vm_drain() {
  asm volatile("s_waitcnt vmcnt(0)" ::: "memory");
}

// Sentinel = 0xFFFF per fp16 (a NaN). Legal h values are sigm*tanh in (-1,1)
// -> never NaN -> never 0xFFFF.
__device__ __forceinline__ bool valid16(uint4 v) {
  return ((v.x & 0xFFFFu) != 0xFFFFu) && ((v.x >> 16) != 0xFFFFu) &&
         ((v.y & 0xFFFFu) != 0xFFFFu) && ((v.y >> 16) != 0xFFFFu) &&
         ((v.z & 0xFFFFu) != 0xFFFFu) && ((v.z >> 16) != 0xFFFFu) &&
         ((v.w & 0xFFFFu) != 0xFFFFu) && ((v.w >> 16) != 0xFFFFu);
}

// h store: 2B write-through agent store (r11-proven form).
__device__ __forceinline__ void h_store(unsigned short* p, unsigned short v) {
  __hip_atomic_store(p, v, __ATOMIC_RELAXED, __HIP_MEMORY_SCOPE_AGENT);
}

// fill a region with the sentinel pattern (grid-stride, uint4 granularity)
__global__ __launch_bounds__(256) void fill_sent_k(uint4* __restrict__ dst, size_t n16) {
  uint4 s = {0xFFFFFFFFu, 0xFFFFFFFFu, 0xFFFFFFFFu, 0xFFFFFFFFu};
  size_t stride = (size_t)gridDim.x * 256;
  for (size_t i = (size_t)blockIdx.x * 256 + threadIdx.x; i < n16; i += stride)
    dst[i] = s;
}

// fp32 -> fp16 convert (4 elems/thread)
__global__ __launch_bounds__(256) void f2h_k(const float* __restrict__ src,
                                             _Float16* __restrict__ dst, int n4) {
  int i = blockIdx.x * 256 + threadIdx.x;
  if (i < n4) {
    float4 v = ((const float4*)src)[i];
    h4 o = {(_Float16)v.x, (_Float16)v.y, (_Float16)v.z, (_Float16)v.w};
    ((h4*)dst)[i] = o;
  }
}

// ---------------- persistent encoder: full-M MFMA + sentinel sync -----------
// 128 blocks = 4 groups (dir x 16-batch half) x 32 blocks of 16 h-cols.
// (r15-proven text: poll-in-place, issue+drain adjacent.)
__global__ __launch_bounds__(256, 1) void enc_coop_k(
    const _Float16* __restrict__ xh,
    const _Float16* __restrict__ WihF, const _Float16* __restrict__ WhhF, const float* __restrict__ bF,
    const _Float16* __restrict__ WihR, const _Float16* __restrict__ WhhR, const float* __restrict__ bR,
    float* __restrict__ cF, float* __restrict__ cR,
    _Float16* __restrict__ hsF, _Float16* __restrict__ hsR)
{
  __shared__ __align__(16) _Float16 cbuf[96][16][8];  // [k8][batch][8]
  __shared__ float zfin[4][16][17];                   // [gate][col][batch]
  __shared__ float cls[16][17];                       // c-state [col][batch]

  const int bid = blockIdx.x;
  const int group = bid >> 5;        // 0..3 = dir*2 + half
  const int dir = group >> 1;
  const int bh0 = (group & 1) << 4;  // batch base: 0 or 16
  const int jb = bid & 31;
  const int c0 = jb << 4;            // 16 h-cols per block
  const int tid = threadIdx.x;
  const int lane = tid & 63;
  const int wv = tid >> 6;           // wave = gate 0..3

  const _Float16* __restrict__ Wih = dir ? WihR : WihF;
  const _Float16* __restrict__ Whh = dir ? WhhR : WhhF;
  const float* __restrict__ bias = dir ? bR : bF;
  _Float16* __restrict__ hs = dir ? hsR : hsF;
  float* __restrict__ cOut = dir ? cR : cF;

  h8 aw[24];
  {
    const int m = lane & 15, kg = lane >> 4;
    const int wrow = wv * H_ + c0 + m;
    const _Float16* wi = Wih + (size_t)wrow * D_;
    const _Float16* wh = Whh + (size_t)wrow * H_;
    #pragma unroll
    for (int tu = 0; tu < 24; ++tu) {
      int k = tu * 32 + kg * 8;
      aw[tu] = (k < 256) ? *(const h8*)(wi + k) : *(const h8*)(wh + (k - 256));
    }
  }

  const int cc = tid & 15, cb = tid >> 4;
  float bvg[4];
  #pragma unroll
  for (int g = 0; g < 4; ++g) bvg[g] = bias[g * H_ + c0 + cc];

  const char* cbase = (const char*)cbuf + (size_t)((lane >> 4) * 256 + (lane & 15) * 16);
  const int sn = tid & 15;
  const int xo = (tid >> 4) * 2;
  const int ho = (tid >> 4) * 4;
  __syncthreads();

  for (int t = 0; t < S_; ++t) {
    const int xi = dir ? (S_ - 1 - t) : t;

    {  // phase 1: stage x (cached loads)
      const _Float16* xp = xh + ((size_t)(bh0 + sn) * S_ + xi) * D_;
      uint4 v0 = *(const uint4*)(xp + xo * 8);
      uint4 v1 = *(const uint4*)(xp + xo * 8 + 8);
      *(uint4*)&cbuf[xo][sn][0] = v0;
      *(uint4*)&cbuf[xo + 1][sn][0] = v1;
    }
    __syncthreads();

    f32x4 acc = {0.f, 0.f, 0.f, 0.f};
    #pragma unroll
    for (int tu = 0; tu < 8; ++tu) {
      h8 bf = *(const h8*)(cbase + tu * 1024);
      acc = __builtin_amdgcn_mfma_f32_16x16x32_f16(aw[tu], bf, acc, 0, 0, 0);
    }

    {  // phase 3: h_{t-1} via sentinel poll (issue+drain ADJACENT)
      if (t == 0) {
        uint4 z = {0, 0, 0, 0};
        #pragma unroll
        for (int u = 0; u < 4; ++u) *(uint4*)&cbuf[32 + ho + u][sn][0] = z;
      } else {
        const int xip = dir ? xi + 1 : xi - 1;
        const _Float16* hbase = hs + ((size_t)xip * B_ + bh0 + sn) * H_;
        uint4 vs[4];
        unsigned pend = 0xF;
        do {
          #pragma unroll
          for (int u = 0; u < 4; ++u)
            if (pend & (1u << u)) vs[u] = coh_load16(hbase + (ho + u) * 8);
          vm_drain();
          #pragma unroll
          for (int u = 0; u < 4; ++u)
            if ((pend & (1u << u)) && valid16(vs[u])) pend &= ~(1u << u);
        } while (pend);
        #pragma unroll
        for (int u = 0; u < 4; ++u) *(uint4*)&cbuf[32 + ho + u][sn][0] = vs[u];
      }
    }
    __syncthreads();

    #pragma unroll
    for (int tu = 8; tu < 24; ++tu) {
      h8 bf = *(const h8*)(cbase + tu * 1024);
      acc = __builtin_amdgcn_mfma_f32_16x16x32_f16(aw[tu], bf, acc, 0, 0, 0);
    }
    {
      const int mrow = (lane >> 4) * 4, n = lane & 15;
      #pragma unroll
      for (int r = 0; r < 4; ++r) zfin[wv][mrow + r][n] = acc[r];
    }
    __syncthreads();

    {  // cell: 16 cols x 16 batches
      const float zi = zfin[0][cc][cb] + bvg[0];
      const float zf = zfin[1][cc][cb] + bvg[1];
      const float zg = zfin[2][cc][cb] + bvg[2];
      const float zo = zfin[3][cc][cb] + bvg[3];
      const float c_old = (t == 0) ? 0.f : cls[cc][cb];
      const float cn = sigm(zf) * c_old + sigm(zi) * tanh_fast(zg);
      const float hn = sigm(zo) * tanh_fast(cn);
      cls[cc][cb] = cn;
      _Float16 hh = (_Float16)hn;
      h_store((unsigned short*)(hs + ((size_t)xi * B_ + bh0 + cb) * H_ + c0 + cc),
              __builtin_bit_cast(unsigned short, hh));
      if (t == S_ - 1) cOut[(size_t)(bh0 + cb) * H_ + c0 + cc] = cn;
    }
    __syncthreads();
  }
}

// ---------------- persistent decoder: full-M MFMA + sentinel sync -----------
// 64 blocks = 2 groups (16-batch halves) x 32 blocks of 16 h-cols. K = 512.
__global__ __launch_bounds__(256, 1) void dec_coop_k(
    const float* __restrict__ hd0, const float* __restrict__ cD0,
    const _Float16* __restrict__ Whh, const float* __restrict__ bias,
    _Float16* __restrict__ hdec)
{
  __shared__ __align__(16) _Float16 cbuf[64][16][8];
  __shared__ float zfin[4][16][17];
  __shared__ float cls[16][17];

  const int bid = blockIdx.x;
  const int group = bid >> 5;
  const int bh0 = group << 4;
  const int jb = bid & 31;
  const int c0 = jb << 4;
  const int tid = threadIdx.x;
  const int lane = tid & 63;
  const int wv = tid >> 6;

  h8 aw[16];
  {
    const int m = lane & 15, kg = lane >> 4;
    const _Float16* wh = Whh + (size_t)(wv * H_ + c0 + m) * H_;
    #pragma unroll
    for (int tu = 0; tu < 16; ++tu) aw[tu] = *(const h8*)(wh + tu * 32 + kg * 8);
  }

  const int cc = tid & 15, cb = tid >> 4;
  float bvg[4];
  #pragma unroll
  for (int g = 0; g < 4; ++g) bvg[g] = bias[g * H_ + c0 + cc];
  cls[cc][cb] = cD0[(size_t)(bh0 + cb) * H_ + c0 + cc];

  const char* cbase = (const char*)cbuf + (size_t)((lane >> 4) * 256 + (lane & 15) * 16);
  const int sn = tid & 15, ho = (tid >> 4) * 4;
  __syncthreads();

  for (int t = 0; t < S_; ++t) {
    {
      if (t == 0) {
        const float* src = hd0 + (size_t)(bh0 + sn) * H_;
        #pragma unroll
        for (int u = 0; u < 4; ++u) {
          float4 f0 = *(const float4*)(src + (ho + u) * 8);
          float4 f1 = *(const float4*)(src + (ho + u) * 8 + 4);
          h8 o = {(_Float16)f0.x, (_Float16)f0.y, (_Float16)f0.z, (_Float16)f0.w,
                  (_Float16)f1.x, (_Float16)f1.y, (_Float16)f1.z, (_Float16)f1.w};
          *(h8*)&cbuf[ho + u][sn][0] = o;
        }
      } else {
        const _Float16* src = hdec + ((size_t)(t - 1) * B_ + bh0 + sn) * H_;
        uint4 vs[4];
        unsigned pend = 0xF;
        do {
          #pragma unroll
          for (int u = 0; u < 4; ++u)
            if (pend & (1u << u)) vs[u] = coh_load16(src + (ho + u) * 8);
          vm_drain();
          #pragma unroll
          for (int u = 0; u < 4; ++u)
            if ((pend & (1u << u)) && valid16(vs[u])) pend &= ~(1u << u);
        } while (pend);
        #pragma unroll
        for (int u = 0; u < 4; ++u) *(uint4*)&cbuf[ho + u][sn][0] = vs[u];
      }
    }
    __syncthreads();

    f32x4 acc = {0.f, 0.f, 0.f, 0.f};
    #pragma unroll
    for (int tu = 0; tu < 16; ++tu) {
      h8 bf = *(const h8*)(cbase + tu * 1024);
      acc = __builtin_amdgcn_mfma_f32_16x16x32_f16(aw[tu], bf, acc, 0, 0, 0);
    }
    {
      const int mrow = (lane >> 4) * 4, n = lane & 15;
      #pragma unroll
      for (int r = 0; r < 4; ++r) zfin[wv][mrow + r][n] = acc[r];
    }
    __syncthreads();

    {
      const float zi = zfin[0][cc][cb] + bvg[0];
      const float zf = zfin[1][cc][cb] + bvg[1];
      const float zg = zfin[2][cc][cb] + bvg[2];
      const float zo = zfin[3][cc][cb] + bvg[3];
      const float cn = sigm(zf) * cls[cc][cb] + sigm(zi) * tanh_fast(zg);
      const float hn = sigm(zo) * tanh_fast(cn);
      cls[cc][cb] = cn;
      _Float16 hh = (_Float16)hn;
      h_store((unsigned short*)(hdec + ((size_t)t * B_ + bh0 + cb) * H_ + c0 + cc),
              __builtin_bit_cast(unsigned short, hh));
    }
    __syncthreads();
  }
}

// ---------------- MFMA tiled GEMM: C[M,512] = op(A1,A2) @ W^T + bias --------
template <int MODE>
__global__ __launch_bounds__(256) void gemm_mfma_k(
    const _Float16* __restrict__ A1, const _Float16* __restrict__ A2,
    const _Float16* __restrict__ W, const float* __restrict__ bias,
    _Float16* __restrict__ C)
{
  __shared__ __align__(16) _Float16 Abuf[4][66][8];
  __shared__ __align__(16) _Float16 Bbuf[4][66][8];
  const int tid = threadIdx.x;
  const int m0 = blockIdx.x * 64, n0 = blockIdx.y * 64;
  const int lane = tid & 63, wv = tid >> 6;
  const int sr = tid >> 2, sk = tid & 3;
  f32x4 acc[4] = {{0.f,0.f,0.f,0.f},{0.f,0.f,0.f,0.f},
                  {0.f,0.f,0.f,0.f},{0.f,0.f,0.f,0.f}};

  for (int kc = 0; kc < H_; kc += 32) {
    __syncthreads();
    {
      uint4 a = *(const uint4*)(A1 + (size_t)(m0 + sr) * H_ + kc + sk * 8);
      if (MODE == 1) {
        uint4 a2 = *(const uint4*)(A2 + (size_t)(m0 + sr) * H_ + kc + sk * 8);
        a.x = U2(H2(a.x) + H2(a2.x)); a.y = U2(H2(a.y) + H2(a2.y));
        a.z = U2(H2(a.z) + H2(a2.z)); a.w = U2(H2(a.w) + H2(a2.w));
      }
      *(uint4*)&Abuf[sk][sr][0] = a;
      uint4 b = *(const uint4*)(W + (size_t)(n0 + sr) * H_ + kc + sk * 8);
      *(uint4*)&Bbuf[sk][sr][0] = b;
    }
    __syncthreads();
    const int fr = lane & 15, kg = lane >> 4;
    h8 af = *(const h8*)&Abuf[kg][wv * 16 + fr][0];
    #pragma unroll
    for (int nt = 0; nt < 4; ++nt) {
      h8 bf = *(const h8*)&Bbuf[kg][nt * 16 + fr][0];
      acc[nt] = __builtin_amdgcn_mfma_f32_16x16x32_f16(af, bf, acc[nt], 0, 0, 0);
    }
  }
  const int fr = lane & 15, fq = lane >> 4;
  #pragma unroll
  for (int nt = 0; nt < 4; ++nt) {
    const int n = n0 + nt * 16 + fr;
    const float bv = bias[n];
    #pragma unroll
    for (int r = 0; r < 4; ++r) {
      const int m = m0 + wv * 16 + fq * 4 + r;
      C[(size_t)m * H_ + n] = (_Float16)(acc[nt][r] + bv);
    }
  }
}

__device__ __forceinline__ float4 load4f(const float* p) { return *(const float4*)p; }
__device__ __forceinline__ float4 load4f(const _Float16* p) {
  uint2 u = *(const uint2*)p;
  h2 a = H2(u.x), b = H2(u.y);
  return make_float4((float)a.x, (float)a.y, (float)b.x, (float)b.y);
}

// small: C[32,512] = concat(A1,A2)@W^T + bias (K = 1024, halves of 512)
template <typename T>
__global__ __launch_bounds__(256) void gemm_cat_small_k(
    const T* __restrict__ A1, const T* __restrict__ A2,
    const float* __restrict__ W, const float* __restrict__ bias,
    float* __restrict__ C)
{
  const int tid = threadIdx.x;
  const int col = tid & 31;
  const int rg  = tid >> 5;
  const int n   = blockIdx.y * 32 + col;
  float acc[4] = {0, 0, 0, 0};
  #pragma unroll
  for (int pass = 0; pass < 2; ++pass) {
    const T* __restrict__ A = pass ? A2 : A1;
    const float4* __restrict__ w4 = (const float4*)(W + (size_t)n * 1024 + pass * 512);
    for (int k4 = 0; k4 < 128; ++k4) {
      float4 w = w4[k4];
      #pragma unroll
      for (int i = 0; i < 4; ++i) {
        int row = rg + (i << 3);
        float4 a = load4f(A + (size_t)row * H_ + k4 * 4);
        acc[i] += w.x * a.x + w.y * a.y + w.z * a.z + w.w * a.w;
      }
    }
  }
  const float bv = bias[n];
  #pragma unroll
  for (int i = 0; i < 4; ++i) {
    int row = rg + (i << 3);
    C[(size_t)row * H_ + n] = acc[i] + bv;
  }
}

__global__ __launch_bounds__(256) void sumv_k(const float* __restrict__ vt,
                                              float* __restrict__ o) {
  __shared__ float sh[4];
  float v = vt[threadIdx.x] + vt[threadIdx.x + 256];
  #pragma unroll
  for (int d = 32; d; d >>= 1) v += __shfl_down(v, d, 64);
  if ((threadIdx.x & 63) == 0) sh[threadIdx.x >> 6] = v;
  __syncthreads();
  if (threadIdx.x == 0) o[0] = sh[0] + sh[1] + sh[2] + sh[3];
}

// logits[b,t,s] = (sumv + bvt) - 2 * sum_h v[h] * rcp(Ep[s,h]*Eq[t,h] + 1)
// Staging transposed (row = tid&15 -> conflict-light writes); inner loop
// reads float4 (b128) -> 4x fewer LDS instructions.
#define KT_ 2.8853900817779268f
__global__ __launch_bounds__(256) void attn_k(
    const _Float16* __restrict__ pre1, const _Float16* __restrict__ Qm,
    const float* __restrict__ vt, const float* __restrict__ bvt,
    const float* __restrict__ sumv, float* __restrict__ out)
{
  __shared__ float sp[16][260];
  __shared__ float sq[16][260];
  __shared__ float sv[256];
  const int b = blockIdx.z, tbase = blockIdx.y << 4, sbase = blockIdx.x << 4;
  const int tid = threadIdx.x;
  const int so = tid & 15, to = tid >> 4;
  float acc0 = 0.f, acc1 = 0.f;
  const float cfin = sumv[0] + bvt[0];

  for (int h0 = 0; h0 < H_; h0 += 256) {
    __syncthreads();
    {
      const int i = tid & 15, hoo = (tid >> 4) * 16;  // row i, h-offset hoo
      const _Float16* qp = Qm + ((size_t)(tbase + i) * B_ + b) * H_ + h0 + hoo;
      const _Float16* pp = pre1 + ((size_t)(sbase + i) * B_ + b) * H_ + h0 + hoo;
      h8 q0 = *(const h8*)qp, q1 = *(const h8*)(qp + 8);
      h8 p0 = *(const h8*)pp, p1 = *(const h8*)(pp + 8);
      #pragma unroll
      for (int j = 0; j < 8; ++j) {
        sq[i][hoo + j]     = exp2_fast(fminf(fmaxf(KT_ * (float)q0[j], -60.f), 60.f));
        sq[i][hoo + 8 + j] = exp2_fast(fminf(fmaxf(KT_ * (float)q1[j], -60.f), 60.f));
        sp[i][hoo + j]     = exp2_fast(fminf(fmaxf(KT_ * (float)p0[j], -60.f), 60.f));
        sp[i][hoo + 8 + j] = exp2_fast(fminf(fmaxf(KT_ * (float)p1[j], -60.f), 60.f));
      }
    }
    sv[tid] = vt[h0 + tid];
    __syncthreads();
    #pragma unroll 8
    for (int h4_ = 0; h4_ < 64; ++h4_) {
      float4 p = *(const float4*)&sp[so][h4_ * 4];
      float4 q = *(const float4*)&sq[to][h4_ * 4];
      float4 vv = *(const float4*)&sv[h4_ * 4];
      acc0 = fmaf(vv.x, rcp_fast(fmaf(p.x, q.x, 1.0f)), acc0);
      acc1 = fmaf(vv.y, rcp_fast(fmaf(p.y, q.y, 1.0f)), acc1);
      acc0 = fmaf(vv.z, rcp_fast(fmaf(p.z, q.z, 1.0f)), acc0);
      acc1 = fmaf(vv.w, rcp_fast(fmaf(p.w, q.w, 1.0f)), acc1);
    }
  }
  out[((size_t)b * S_ + tbase + to) * S_ + sbase + so] = cfin - 2.f * (acc0 + acc1);
}

extern "C" void kernel_launch(void* const* d_in, const int* in_sizes, int n_in,
                              void* d_out, int out_size, void* d_ws, size_t ws_size,
                              hipStream_t stream)
{
  (void)in_sizes; (void)n_in; (void)out_size; (void)ws_size;
  const float* x     = (const float*)d_in[0];
  const float* WihF  = (const float*)d_in[1];
  const float* WhhF  = (const float*)d_in[2];
  const float* bF    = (const float*)d_in[3];
  const float* WihR  = (const float*)d_in[4];
  const float* WhhR  = (const float*)d_in[5];
  const float* bR    = (const float*)d_in[6];
  /* d_in[7] = Wih_d unused by reference decoder */
  const float* WhhD  = (const float*)d_in[8];
  const float* bD    = (const float*)d_in[9];
  const float* Wr_h  = (const float*)d_in[10];
  const float* br_h  = (const float*)d_in[11];
  const float* Wr_c  = (const float*)d_in[12];
  const float* br_c  = (const float*)d_in[13];
  const float* W1    = (const float*)d_in[14];
  const float* b1    = (const float*)d_in[15];
  const float* W2    = (const float*)d_in[16];
  const float* b2    = (const float*)d_in[17];
  const float* vt    = (const float*)d_in[18];
  const float* bvt   = (const float*)d_in[19];
  float* out = (float*)d_out;

  const size_t SBH = (size_t)S_ * B_ * H_;   // 8,388,608
  const size_t BH  = (size_t)B_ * H_;

  _Float16* hp = (_Float16*)d_ws;
  _Float16* hs_f  = hp;              hp += SBH;   // sentinel-filled
  _Float16* hs_r  = hp;              hp += SBH;   // sentinel-filled
  _Float16* hdec  = hp;              hp += SBH;   // sentinel-filled
  _Float16* pre1h = hp;              hp += SBH;
  _Float16* Qmh   = hp;              hp += SBH;
  _Float16* xh    = hp;              hp += (size_t)B_ * S_ * D_;
  _Float16* wihF  = hp;              hp += (size_t)4 * H_ * D_;
  _Float16* wihR  = hp;              hp += (size_t)4 * H_ * D_;
  _Float16* whhF  = hp;              hp += (size_t)4 * H_ * H_;
  _Float16* whhR  = hp;              hp += (size_t)4 * H_ * H_;
  _Float16* whhD  = hp;              hp += (size_t)4 * H_ * H_;
  _Float16* w1h   = hp;              hp += (size_t)H_ * H_;
  _Float16* w2h   = hp;              hp += (size_t)H_ * H_;
  float* fp  = (float*)hp;
  float* cF  = fp;                   fp += BH;
  float* cR  = fp;                   fp += BH;
  float* cD  = fp;                   fp += BH;
  float* hd0 = fp;                   fp += BH;
  float* sumv = fp;

  // sentinel-fill the three h-exchange buffers
  fill_sent_k<<<2048, 256, 0, stream>>>((uint4*)hs_f, 3 * SBH / 8);

  // fp32 -> fp16 converts
  f2h_k<<<(B_ * S_ * D_ / 4 + 255) / 256, 256, 0, stream>>>(x, xh, B_ * S_ * D_ / 4);
  f2h_k<<<(4 * H_ * D_ / 4 + 255) / 256, 256, 0, stream>>>(WihF, wihF, 4 * H_ * D_ / 4);
  f2h_k<<<(4 * H_ * D_ / 4 + 255) / 256, 256, 0, stream>>>(WihR, wihR, 4 * H_ * D_ / 4);
  f2h_k<<<(4 * H_ * H_ / 4 + 255) / 256, 256, 0, stream>>>(WhhF, whhF, 4 * H_ * H_ / 4);
  f2h_k<<<(4 * H_ * H_ / 4 + 255) / 256, 256, 0, stream>>>(WhhR, whhR, 4 * H_ * H_ / 4);
  f2h_k<<<(4 * H_ * H_ / 4 + 255) / 256, 256, 0, stream>>>(WhhD, whhD, 4 * H_ * H_ / 4);
  f2h_k<<<(H_ * H_ / 4 + 255) / 256, 256, 0, stream>>>(W1, w1h, H_ * H_ / 4);
  f2h_k<<<(H_ * H_ / 4 + 255) / 256, 256, 0, stream>>>(W2, w2h, H_ * H_ / 4);
  sumv_k<<<1, 256, 0, stream>>>(vt, sumv);

  // encoder: persistent full-M MFMA, sentinel dataflow sync (128 blocks)
  enc_coop_k<<<128, 256, 0, stream>>>(xh, wihF, whhF, bF, wihR, whhR, bR,
                                      cF, cR, hs_f, hs_r);

  // decoder init
  gemm_cat_small_k<_Float16><<<dim3(1, 16), 256, 0, stream>>>(
      hs_f + (size_t)(S_ - 1) * BH, hs_r, Wr_h, br_h, hd0);
  gemm_cat_small_k<float><<<dim3(1, 16), 256, 0, stream>>>(cF, cR, Wr_c, br_c, cD);

  // pre1 = (hs_f + hs_r) @ W1^T + b1   (MFMA)
  gemm_mfma_k<1><<<dim3(256, 8), 256, 0, stream>>>(hs_f, hs_r, w1h, b1, pre1h);

  // decoder: persistent full-M MFMA, sentinel dataflow sync (64 blocks)
  dec_coop_k<<<64, 256, 0, stream>>>(hd0, cD, whhD, bD, hdec);

  // Q = Hdec @ W2^T + b2   (MFMA)
  gemm_mfma_k<0><<<dim3(256, 8), 256, 0, stream>>>(hdec, nullptr, w2h, b2, Qmh);

  // attention (exp-product tanh, transposed staging + float4 reads)
  attn_k<<<dim3(32, 32, 32), 256, 0, stream>>>(pre1h, Qmh, vt, bvt, sumv, out);
}

// Round 18
// 3330.538 us; speedup vs baseline: 1.8271x; 1.0131x over previous
//
#include <hip/hip_runtime.h>
#include <hip/hip_bf16.h>
#include <cstdint>
#include <cstddef>

#define B_ 32
#define S_ 512
#define D_ 256
#define H_ 512

typedef _Float16 h2 __attribute__((ext_vector_type(2)));
typedef _Float16 h4 __attribute__((ext_vector_type(4)));
typedef _Float16 h8 __attribute__((ext_vector_type(8)));
typedef float f32x4 __attribute__((ext_vector_type(4)));
typedef unsigned u32x4 __attribute__((ext_vector_type(4)));

__device__ __forceinline__ h2 H2(unsigned u) { return __builtin_bit_cast(h2, u); }
__device__ __forceinline__ unsigned U2(h2 v) { return __builtin_bit_cast(unsigned, v); }

#if __has_builtin(__builtin_amdgcn_exp2f)
__device__ __forceinline__ float exp2_fast(float x) { return __builtin_amdgcn_exp2f(x); }
#else
__device__ __forceinline__ float exp2_fast(float x) { return exp2f(x); }
#endif
#if __has_builtin(__builtin_amdgcn_rcpf)
__device__ __forceinline__ float rcp_fast(float x) { return __builtin_amdgcn_rcpf(x); }
#else
__device__ __forceinline__ float rcp_fast(float x) { return 1.0f / x; }
#endif

__device__ __forceinline__ float sigm(float x) {
  return rcp_fast(1.0f + exp2_fast(-1.4426950408889634f * x));
}
__device__ __forceinline__ float tanh_fast(float x) {
  return 1.0f - 2.0f * rcp_fast(1.0f + exp2_fast(2.8853900817779268f * x));
}

// Coherent 16B load (bypass L1/L2, read L3). MUST be drained (vm_drain)
// IMMEDIATELY after issue, before any other code touches the outputs:
// the compiler does not model vmcnt for inline-asm outputs (r16 lesson).
__device__ __forceinline__ uint4 coh_load16(const void* p) {
  u32x4 v;
  asm volatile("global_load_dwordx4 %0, %1, off sc0 sc1"
               : "=v"(v) : "v"(p) : "memory");
  return __builtin_bit_cast(uint4, v);
}
__device__ __forceinline__ void vm_drain() {
  asm volatile("s_waitcnt vmcnt(0)" ::: "memory");
}

// Sentinel = 0xFFFF per fp16 (a NaN). Legal h values are sigm*tanh in (-1,1)
// -> never NaN -> never 0xFFFF.
__device__ __forceinline__ bool valid16(uint4 v) {
  return ((v.x & 0xFFFFu) != 0xFFFFu) && ((v.x >> 16) != 0xFFFFu) &&
         ((v.y & 0xFFFFu) != 0xFFFFu) && ((v.y >> 16) != 0xFFFFu) &&
         ((v.z & 0xFFFFu) != 0xFFFFu) && ((v.z >> 16) != 0xFFFFu) &&
         ((v.w & 0xFFFFu) != 0xFFFFu) && ((v.w >> 16) != 0xFFFFu);
}

// h store: 2B write-through agent store (r11-proven form).
__device__ __forceinline__ void h_store(unsigned short* p, unsigned short v) {
  __hip_atomic_store(p, v, __ATOMIC_RELAXED, __HIP_MEMORY_SCOPE_AGENT);
}

// ---------------- fused preamble: sentinel fill + all fp32->fp16 converts ---
// Segment table is compile-time; grid-stride over fill then convert items.
#define N_X   1048576u   // B*S*D/4
#define N_WIH 131072u    // 4*H*D/4
#define N_WHH 262144u    // 4*H*H/4
#define N_W1  65536u     // H*H/4
#define C0_ N_X
#define C1_ (C0_ + N_WIH)
#define C2_ (C1_ + N_WIH)
#define C3_ (C2_ + N_WHH)
#define C4_ (C3_ + N_WHH)
#define C5_ (C4_ + N_WHH)
#define C6_ (C5_ + N_W1)
#define NCV (C6_ + N_W1)
__global__ __launch_bounds__(256) void prep_k(
    const float* __restrict__ x,
    const float* __restrict__ WihF, const float* __restrict__ WihR,
    const float* __restrict__ WhhF, const float* __restrict__ WhhR,
    const float* __restrict__ WhhD,
    const float* __restrict__ W1, const float* __restrict__ W2,
    _Float16* __restrict__ xh, _Float16* __restrict__ wihF, _Float16* __restrict__ wihR,
    _Float16* __restrict__ whhF, _Float16* __restrict__ whhR, _Float16* __restrict__ whhD,
    _Float16* __restrict__ w1h, _Float16* __restrict__ w2h,
    uint4* __restrict__ sent)
{
  const size_t stride = (size_t)gridDim.x * 256;
  const size_t NS = 3ull * S_ * B_ * H_ / 8;   // 3,145,728 uint4
  uint4 sv = {0xFFFFFFFFu, 0xFFFFFFFFu, 0xFFFFFFFFu, 0xFFFFFFFFu};
  for (size_t j = (size_t)blockIdx.x * 256 + threadIdx.x; j < NS; j += stride)
    sent[j] = sv;
  for (size_t j = (size_t)blockIdx.x * 256 + threadIdx.x; j < NCV; j += stride) {
    const float* src; _Float16* dst; size_t off;
    if (j < C0_)      { src = x;    dst = xh;   off = j; }
    else if (j < C1_) { src = WihF; dst = wihF; off = j - C0_; }
    else if (j < C2_) { src = WihR; dst = wihR; off = j - C1_; }
    else if (j < C3_) { src = WhhF; dst = whhF; off = j - C2_; }
    else if (j < C4_) { src = WhhR; dst = whhR; off = j - C3_; }
    else if (j < C5_) { src = WhhD; dst = whhD; off = j - C4_; }
    else if (j < C6_) { src = W1;   dst = w1h;  off = j - C5_; }
    else              { src = W2;   dst = w2h;  off = j - C6_; }
    float4 v = ((const float4*)src)[off];
    h4 o = {(_Float16)v.x, (_Float16)v.y, (_Float16)v.z, (_Float16)v.w};
    ((h4*)dst)[off] = o;
  }
}

// ---------------- persistent encoder: full-M MFMA + sentinel sync -----------
// 128 blocks = 4 groups (dir x 16-batch half) x 32 blocks of 16 h-cols.
// 3 barriers/step (post-cell barrier proven redundant); dual accumulators.
__global__ __launch_bounds__(256, 1) void enc_coop_k(
    const _Float16* __restrict__ xh,
    const _Float16* __restrict__ WihF, const _Float16* __restrict__ WhhF, const float* __restrict__ bF,
    const _Float16* __restrict__ WihR, const _Float16* __restrict__ WhhR, const float* __restrict__ bR,
    float* __restrict__ cF, float* __restrict__ cR,
    _Float16* __restrict__ hsF, _Float16* __restrict__ hsR)
{
  __shared__ __align__(16) _Float16 cbuf[96][16][8];  // [k8][batch][8]
  __shared__ float zfin[4][16][17];                   // [gate][col][batch]
  __shared__ float cls[16][17];                       // c-state [col][batch]

  const int bid = blockIdx.x;
  const int group = bid >> 5;        // 0..3 = dir*2 + half
  const int dir = group >> 1;
  const int bh0 = (group & 1) << 4;  // batch base: 0 or 16
  const int jb = bid & 31;
  const int c0 = jb << 4;            // 16 h-cols per block
  const int tid = threadIdx.x;
  const int lane = tid & 63;
  const int wv = tid >> 6;           // wave = gate 0..3

  const _Float16* __restrict__ Wih = dir ? WihR : WihF;
  const _Float16* __restrict__ Whh = dir ? WhhR : WhhF;
  const float* __restrict__ bias = dir ? bR : bF;
  _Float16* __restrict__ hs = dir ? hsR : hsF;
  float* __restrict__ cOut = dir ? cR : cF;

  h8 aw[24];
  {
    const int m = lane & 15, kg = lane >> 4;
    const int wrow = wv * H_ + c0 + m;
    const _Float16* wi = Wih + (size_t)wrow * D_;
    const _Float16* wh = Whh + (size_t)wrow * H_;
    #pragma unroll
    for (int tu = 0; tu < 24; ++tu) {
      int k = tu * 32 + kg * 8;
      aw[tu] = (k < 256) ? *(const h8*)(wi + k) : *(const h8*)(wh + (k - 256));
    }
  }

  const int cc = tid & 15, cb = tid >> 4;
  float bvg[4];
  #pragma unroll
  for (int g = 0; g < 4; ++g) bvg[g] = bias[g * H_ + c0 + cc];

  const char* cbase = (const char*)cbuf + (size_t)((lane >> 4) * 256 + (lane & 15) * 16);
  const int sn = tid & 15;
  const int xo = (tid >> 4) * 2;
  const int ho = (tid >> 4) * 4;
  __syncthreads();

  for (int t = 0; t < S_; ++t) {
    const int xi = dir ? (S_ - 1 - t) : t;

    {  // phase 1: stage x (cached loads)
      const _Float16* xp = xh + ((size_t)(bh0 + sn) * S_ + xi) * D_;
      uint4 v0 = *(const uint4*)(xp + xo * 8);
      uint4 v1 = *(const uint4*)(xp + xo * 8 + 8);
      *(uint4*)&cbuf[xo][sn][0] = v0;
      *(uint4*)&cbuf[xo + 1][sn][0] = v1;
    }
    __syncthreads();

    // phase 2: x-part MFMA (dual independent accumulator chains)
    f32x4 acc0 = {0.f, 0.f, 0.f, 0.f}, acc1 = {0.f, 0.f, 0.f, 0.f};
    #pragma unroll
    for (int tu = 0; tu < 8; tu += 2) {
      h8 b0 = *(const h8*)(cbase + tu * 1024);
      h8 b1 = *(const h8*)(cbase + (tu + 1) * 1024);
      acc0 = __builtin_amdgcn_mfma_f32_16x16x32_f16(aw[tu], b0, acc0, 0, 0, 0);
      acc1 = __builtin_amdgcn_mfma_f32_16x16x32_f16(aw[tu + 1], b1, acc1, 0, 0, 0);
    }

    {  // phase 3: h_{t-1} via sentinel poll (issue+drain ADJACENT)
      if (t == 0) {
        uint4 z = {0, 0, 0, 0};
        #pragma unroll
        for (int u = 0; u < 4; ++u) *(uint4*)&cbuf[32 + ho + u][sn][0] = z;
      } else {
        const int xip = dir ? xi + 1 : xi - 1;
        const _Float16* hbase = hs + ((size_t)xip * B_ + bh0 + sn) * H_;
        uint4 vs[4];
        unsigned pend = 0xF;
        do {
          #pragma unroll
          for (int u = 0; u < 4; ++u)
            if (pend & (1u << u)) vs[u] = coh_load16(hbase + (ho + u) * 8);
          vm_drain();
          #pragma unroll
          for (int u = 0; u < 4; ++u)
            if ((pend & (1u << u)) && valid16(vs[u])) pend &= ~(1u << u);
        } while (pend);
        #pragma unroll
        for (int u = 0; u < 4; ++u) *(uint4*)&cbuf[32 + ho + u][sn][0] = vs[u];
      }
    }
    __syncthreads();

    // phase 4: h-part MFMA (alternating chains)
    #pragma unroll
    for (int tu = 8; tu < 24; tu += 2) {
      h8 b0 = *(const h8*)(cbase + tu * 1024);
      h8 b1 = *(const h8*)(cbase + (tu + 1) * 1024);
      acc0 = __builtin_amdgcn_mfma_f32_16x16x32_f16(aw[tu], b0, acc0, 0, 0, 0);
      acc1 = __builtin_amdgcn_mfma_f32_16x16x32_f16(aw[tu + 1], b1, acc1, 0, 0, 0);
    }
    {
      const int mrow = (lane >> 4) * 4, n = lane & 15;
      #pragma unroll
      for (int r = 0; r < 4; ++r) zfin[wv][mrow + r][n] = acc0[r] + acc1[r];
    }
    __syncthreads();

    {  // cell: 16 cols x 16 batches (no trailing barrier: next sync1 orders)
      const float zi = zfin[0][cc][cb] + bvg[0];
      const float zf = zfin[1][cc][cb] + bvg[1];
      const float zg = zfin[2][cc][cb] + bvg[2];
      const float zo = zfin[3][cc][cb] + bvg[3];
      const float c_old = (t == 0) ? 0.f : cls[cc][cb];
      const float cn = sigm(zf) * c_old + sigm(zi) * tanh_fast(zg);
      const float hn = sigm(zo) * tanh_fast(cn);
      cls[cc][cb] = cn;
      _Float16 hh = (_Float16)hn;
      h_store((unsigned short*)(hs + ((size_t)xi * B_ + bh0 + cb) * H_ + c0 + cc),
              __builtin_bit_cast(unsigned short, hh));
      if (t == S_ - 1) cOut[(size_t)(bh0 + cb) * H_ + c0 + cc] = cn;
    }
  }
}

// ---------------- persistent decoder: full-M MFMA + sentinel sync -----------
// 64 blocks = 2 groups (16-batch halves) x 32 blocks of 16 h-cols. K = 512.
// 2 barriers/step; dual accumulators.
__global__ __launch_bounds__(256, 1) void dec_coop_k(
    const float* __restrict__ hd0, const float* __restrict__ cD0,
    const _Float16* __restrict__ Whh, const float* __restrict__ bias,
    _Float16* __restrict__ hdec)
{
  __shared__ __align__(16) _Float16 cbuf[64][16][8];
  __shared__ float zfin[4][16][17];
  __shared__ float cls[16][17];

  const int bid = blockIdx.x;
  const int group = bid >> 5;
  const int bh0 = group << 4;
  const int jb = bid & 31;
  const int c0 = jb << 4;
  const int tid = threadIdx.x;
  const int lane = tid & 63;
  const int wv = tid >> 6;

  h8 aw[16];
  {
    const int m = lane & 15, kg = lane >> 4;
    const _Float16* wh = Whh + (size_t)(wv * H_ + c0 + m) * H_;
    #pragma unroll
    for (int tu = 0; tu < 16; ++tu) aw[tu] = *(const h8*)(wh + tu * 32 + kg * 8);
  }

  const int cc = tid & 15, cb = tid >> 4;
  float bvg[4];
  #pragma unroll
  for (int g = 0; g < 4; ++g) bvg[g] = bias[g * H_ + c0 + cc];
  cls[cc][cb] = cD0[(size_t)(bh0 + cb) * H_ + c0 + cc];

  const char* cbase = (const char*)cbuf + (size_t)((lane >> 4) * 256 + (lane & 15) * 16);
  const int sn = tid & 15, ho = (tid >> 4) * 4;
  __syncthreads();

  for (int t = 0; t < S_; ++t) {
    {
      if (t == 0) {
        const float* src = hd0 + (size_t)(bh0 + sn) * H_;
        #pragma unroll
        for (int u = 0; u < 4; ++u) {
          float4 f0 = *(const float4*)(src + (ho + u) * 8);
          float4 f1 = *(const float4*)(src + (ho + u) * 8 + 4);
          h8 o = {(_Float16)f0.x, (_Float16)f0.y, (_Float16)f0.z, (_Float16)f0.w,
                  (_Float16)f1.x, (_Float16)f1.y, (_Float16)f1.z, (_Float16)f1.w};
          *(h8*)&cbuf[ho + u][sn][0] = o;
        }
      } else {
        const _Float16* src = hdec + ((size_t)(t - 1) * B_ + bh0 + sn) * H_;
        uint4 vs[4];
        unsigned pend = 0xF;
        do {
          #pragma unroll
          for (int u = 0; u < 4; ++u)
            if (pend & (1u << u)) vs[u] = coh_load16(src + (ho + u) * 8);
          vm_drain();
          #pragma unroll
          for (int u = 0; u < 4; ++u)
            if ((pend & (1u << u)) && valid16(vs[u])) pend &= ~(1u << u);
        } while (pend);
        #pragma unroll
        for (int u = 0; u < 4; ++u) *(uint4*)&cbuf[ho + u][sn][0] = vs[u];
      }
    }
    __syncthreads();

    f32x4 acc0 = {0.f, 0.f, 0.f, 0.f}, acc1 = {0.f, 0.f, 0.f, 0.f};
    #pragma unroll
    for (int tu = 0; tu < 16; tu += 2) {
      h8 b0 = *(const h8*)(cbase + tu * 1024);
      h8 b1 = *(const h8*)(cbase + (tu + 1) * 1024);
      acc0 = __builtin_amdgcn_mfma_f32_16x16x32_f16(aw[tu], b0, acc0, 0, 0, 0);
      acc1 = __builtin_amdgcn_mfma_f32_16x16x32_f16(aw[tu + 1], b1, acc1, 0, 0, 0);
    }
    {
      const int mrow = (lane >> 4) * 4, n = lane & 15;
      #pragma unroll
      for (int r = 0; r < 4; ++r) zfin[wv][mrow + r][n] = acc0[r] + acc1[r];
    }
    __syncthreads();

    {  // cell (no trailing barrier: next-iteration first barrier orders)
      const float zi = zfin[0][cc][cb] + bvg[0];
      const float zf = zfin[1][cc][cb] + bvg[1];
      const float zg = zfin[2][cc][cb] + bvg[2];
      const float zo = zfin[3][cc][cb] + bvg[3];
      const float cn = sigm(zf) * cls[cc][cb] + sigm(zi) * tanh_fast(zg);
      const float hn = sigm(zo) * tanh_fast(cn);
      cls[cc][cb] = cn;
      _Float16 hh = (_Float16)hn;
      h_store((unsigned short*)(hdec + ((size_t)t * B_ + bh0 + cb) * H_ + c0 + cc),
              __builtin_bit_cast(unsigned short, hh));
    }
  }
}

// ---------------- MFMA tiled GEMM: C[M,512] = op(A1,A2) @ W^T + bias --------
template <int MODE>
__global__ __launch_bounds__(256) void gemm_mfma_k(
    const _Float16* __restrict__ A1, const _Float16* __restrict__ A2,
    const _Float16* __restrict__ W, const float* __restrict__ bias,
    _Float16* __restrict__ C)
{
  __shared__ __align__(16) _Float16 Abuf[4][66][8];
  __shared__ __align__(16) _Float16 Bbuf[4][66][8];
  const int tid = threadIdx.x;
  const int m0 = blockIdx.x * 64, n0 = blockIdx.y * 64;
  const int lane = tid & 63, wv = tid >> 6;
  const int sr = tid >> 2, sk = tid & 3;
  f32x4 acc[4] = {{0.f,0.f,0.f,0.f},{0.f,0.f,0.f,0.f},
                  {0.f,0.f,0.f,0.f},{0.f,0.f,0.f,0.f}};

  for (int kc = 0; kc < H_; kc += 32) {
    __syncthreads();
    {
      uint4 a = *(const uint4*)(A1 + (size_t)(m0 + sr) * H_ + kc + sk * 8);
      if (MODE == 1) {
        uint4 a2 = *(const uint4*)(A2 + (size_t)(m0 + sr) * H_ + kc + sk * 8);
        a.x = U2(H2(a.x) + H2(a2.x)); a.y = U2(H2(a.y) + H2(a2.y));
        a.z = U2(H2(a.z) + H2(a2.z)); a.w = U2(H2(a.w) + H2(a2.w));
      }
      *(uint4*)&Abuf[sk][sr][0] = a;
      uint4 b = *(const uint4*)(W + (size_t)(n0 + sr) * H_ + kc + sk * 8);
      *(uint4*)&Bbuf[sk][sr][0] = b;
    }
    __syncthreads();
    const int fr = lane & 15, kg = lane >> 4;
    h8 af = *(const h8*)&Abuf[kg][wv * 16 + fr][0];
    #pragma unroll
    for (int nt = 0; nt < 4; ++nt) {
      h8 bf = *(const h8*)&Bbuf[kg][nt * 16 + fr][0];
      acc[nt] = __builtin_amdgcn_mfma_f32_16x16x32_f16(af, bf, acc[nt], 0, 0, 0);
    }
  }
  const int fr = lane & 15, fq = lane >> 4;
  #pragma unroll
  for (int nt = 0; nt < 4; ++nt) {
    const int n = n0 + nt * 16 + fr;
    const float bv = bias[n];
    #pragma unroll
    for (int r = 0; r < 4; ++r) {
      const int m = m0 + wv * 16 + fq * 4 + r;
      C[(size_t)m * H_ + n] = (_Float16)(acc[nt][r] + bv);
    }
  }
}

__device__ __forceinline__ float4 load4f(const float* p) { return *(const float4*)p; }
__device__ __forceinline__ float4 load4f(const _Float16* p) {
  uint2 u = *(const uint2*)p;
  h2 a = H2(u.x), b = H2(u.y);
  return make_float4((float)a.x, (float)a.y, (float)b.x, (float)b.y);
}

// merged decoder-init: y<16 -> hd0 = [hf|hr]@Wr_h^T+br_h (fp16 A);
//                      y>=16 -> cD = [cF|cR]@Wr_c^T+br_c (fp32 A)
__global__ __launch_bounds__(256) void dec_init_k(
    const _Float16* __restrict__ hfl, const _Float16* __restrict__ hr,
    const float* __restrict__ cF, const float* __restrict__ cR,
    const float* __restrict__ Wr_h, const float* __restrict__ br_h,
    const float* __restrict__ Wr_c, const float* __restrict__ br_c,
    float* __restrict__ hd0, float* __restrict__ cD)
{
  const int tid = threadIdx.x;
  const int col = tid & 31;
  const int rg  = tid >> 5;
  const int which = (int)blockIdx.y >> 4;
  const int n = ((int)blockIdx.y & 15) * 32 + col;
  const float* W = which ? Wr_c : Wr_h;
  const float* bias = which ? br_c : br_h;
  float* C = which ? cD : hd0;
  float acc[4] = {0, 0, 0, 0};
  #pragma unroll
  for (int pass = 0; pass < 2; ++pass) {
    const float4* __restrict__ w4 = (const float4*)(W + (size_t)n * 1024 + pass * 512);
    if (which) {
      const float* A = pass ? cR : cF;
      for (int k4 = 0; k4 < 128; ++k4) {
        float4 w = w4[k4];
        #pragma unroll
        for (int i = 0; i < 4; ++i) {
          int row = rg + (i << 3);
          float4 a = load4f(A + (size_t)row * H_ + k4 * 4);
          acc[i] += w.x * a.x + w.y * a.y + w.z * a.z + w.w * a.w;
        }
      }
    } else {
      const _Float16* A = pass ? hr : hfl;
      for (int k4 = 0; k4 < 128; ++k4) {
        float4 w = w4[k4];
        #pragma unroll
        for (int i = 0; i < 4; ++i) {
          int row = rg + (i << 3);
          float4 a = load4f(A + (size_t)row * H_ + k4 * 4);
          acc[i] += w.x * a.x + w.y * a.y + w.z * a.z + w.w * a.w;
        }
      }
    }
  }
  const float bv = bias[n];
  #pragma unroll
  for (int i = 0; i < 4; ++i) {
    int row = rg + (i << 3);
    C[(size_t)row * H_ + n] = acc[i] + bv;
  }
}

__global__ __launch_bounds__(256) void sumv_k(const float* __restrict__ vt,
                                              float* __restrict__ o) {
  __shared__ float sh[4];
  float v = vt[threadIdx.x] + vt[threadIdx.x + 256];
  #pragma unroll
  for (int d = 32; d; d >>= 1) v += __shfl_down(v, d, 64);
  if ((threadIdx.x & 63) == 0) sh[threadIdx.x >> 6] = v;
  __syncthreads();
  if (threadIdx.x == 0) o[0] = sh[0] + sh[1] + sh[2] + sh[3];
}

// logits[b,t,s] = (sumv + bvt) - 2 * sum_h v[h] * rcp(Ep[s,h]*Eq[t,h] + 1)
#define KT_ 2.8853900817779268f
__global__ __launch_bounds__(256) void attn_k(
    const _Float16* __restrict__ pre1, const _Float16* __restrict__ Qm,
    const float* __restrict__ vt, const float* __restrict__ bvt,
    const float* __restrict__ sumv, float* __restrict__ out)
{
  __shared__ float sp[16][260];
  __shared__ float sq[16][260];
  __shared__ float sv[256];
  const int b = blockIdx.z, tbase = blockIdx.y << 4, sbase = blockIdx.x << 4;
  const int tid = threadIdx.x;
  const int so = tid & 15, to = tid >> 4;
  float acc0 = 0.f, acc1 = 0.f;
  const float cfin = sumv[0] + bvt[0];

  for (int h0 = 0; h0 < H_; h0 += 256) {
    __syncthreads();
    {
      const int i = tid & 15, hoo = (tid >> 4) * 16;
      const _Float16* qp = Qm + ((size_t)(tbase + i) * B_ + b) * H_ + h0 + hoo;
      const _Float16* pp = pre1 + ((size_t)(sbase + i) * B_ + b) * H_ + h0 + hoo;
      h8 q0 = *(const h8*)qp, q1 = *(const h8*)(qp + 8);
      h8 p0 = *(const h8*)pp, p1 = *(const h8*)(pp + 8);
      #pragma unroll
      for (int j = 0; j < 8; ++j) {
        sq[i][hoo + j]     = exp2_fast(fminf(fmaxf(KT_ * (float)q0[j], -60.f), 60.f));
        sq[i][hoo + 8 + j] = exp2_fast(fminf(fmaxf(KT_ * (float)q1[j], -60.f), 60.f));
        sp[i][hoo + j]     = exp2_fast(fminf(fmaxf(KT_ * (float)p0[j], -60.f), 60.f));
        sp[i][hoo + 8 + j] = exp2_fast(fminf(fmaxf(KT_ * (float)p1[j], -60.f), 60.f));
      }
    }
    sv[tid] = vt[h0 + tid];
    __syncthreads();
    #pragma unroll 8
    for (int h4_ = 0; h4_ < 64; ++h4_) {
      float4 p = *(const float4*)&sp[so][h4_ * 4];
      float4 q = *(const float4*)&sq[to][h4_ * 4];
      float4 vv = *(const float4*)&sv[h4_ * 4];
      acc0 = fmaf(vv.x, rcp_fast(fmaf(p.x, q.x, 1.0f)), acc0);
      acc1 = fmaf(vv.y, rcp_fast(fmaf(p.y, q.y, 1.0f)), acc1);
      acc0 = fmaf(vv.z, rcp_fast(fmaf(p.z, q.z, 1.0f)), acc0);
      acc1 = fmaf(vv.w, rcp_fast(fmaf(p.w, q.w, 1.0f)), acc1);
    }
  }
  out[((size_t)b * S_ + tbase + to) * S_ + sbase + so] = cfin - 2.f * (acc0 + acc1);
}

extern "C" void kernel_launch(void* const* d_in, const int* in_sizes, int n_in,
                              void* d_out, int out_size, void* d_ws, size_t ws_size,
                              hipStream_t stream)
{
  (void)in_sizes; (void)n_in; (void)out_size; (void)ws_size;
  const float* x     = (const float*)d_in[0];
  const float* WihF  = (const float*)d_in[1];
  const float* WhhF  = (const float*)d_in[2];
  const float* bF    = (const float*)d_in[3];
  const float* WihR  = (const float*)d_in[4];
  const float* WhhR  = (const float*)d_in[5];
  const float* bR    = (const float*)d_in[6];
  /* d_in[7] = Wih_d unused by reference decoder */
  const float* WhhD  = (const float*)d_in[8];
  const float* bD    = (const float*)d_in[9];
  const float* Wr_h  = (const float*)d_in[10];
  const float* br_h  = (const float*)d_in[11];
  const float* Wr_c  = (const float*)d_in[12];
  const float* br_c  = (const float*)d_in[13];
  const float* W1    = (const float*)d_in[14];
  const float* b1    = (const float*)d_in[15];
  const float* W2    = (const float*)d_in[16];
  const float* b2    = (const float*)d_in[17];
  const float* vt    = (const float*)d_in[18];
  const float* bvt   = (const float*)d_in[19];
  float* out = (float*)d_out;

  const size_t SBH = (size_t)S_ * B_ * H_;   // 8,388,608
  const size_t BH  = (size_t)B_ * H_;

  _Float16* hp = (_Float16*)d_ws;
  _Float16* hs_f  = hp;              hp += SBH;   // sentinel-filled
  _Float16* hs_r  = hp;              hp += SBH;   // sentinel-filled
  _Float16* hdec  = hp;              hp += SBH;   // sentinel-filled
  _Float16* pre1h = hp;              hp += SBH;
  _Float16* Qmh   = hp;              hp += SBH;
  _Float16* xh    = hp;              hp += (size_t)B_ * S_ * D_;
  _Float16* wihF  = hp;              hp += (size_t)4 * H_ * D_;
  _Float16* wihR  = hp;              hp += (size_t)4 * H_ * D_;
  _Float16* whhF  = hp;              hp += (size_t)4 * H_ * H_;
  _Float16* whhR  = hp;              hp += (size_t)4 * H_ * H_;
  _Float16* whhD  = hp;              hp += (size_t)4 * H_ * H_;
  _Float16* w1h   = hp;              hp += (size_t)H_ * H_;
  _Float16* w2h   = hp;              hp += (size_t)H_ * H_;
  float* fp  = (float*)hp;
  float* cF  = fp;                   fp += BH;
  float* cR  = fp;                   fp += BH;
  float* cD  = fp;                   fp += BH;
  float* hd0 = fp;                   fp += BH;
  float* sumv = fp;

  // fused preamble: sentinel fill + all converts (one launch)
  prep_k<<<2048, 256, 0, stream>>>(x, WihF, WihR, WhhF, WhhR, WhhD, W1, W2,
                                   xh, wihF, wihR, whhF, whhR, whhD, w1h, w2h,
                                   (uint4*)hs_f);
  sumv_k<<<1, 256, 0, stream>>>(vt, sumv);

  // encoder: persistent full-M MFMA, sentinel dataflow sync (128 blocks)
  enc_coop_k<<<128, 256, 0, stream>>>(xh, wihF, whhF, bF, wihR, whhR, bR,
                                      cF, cR, hs_f, hs_r);

  // decoder init (merged hd0 + cD)
  dec_init_k<<<dim3(1, 32), 256, 0, stream>>>(
      hs_f + (size_t)(S_ - 1) * BH, hs_r, cF, cR,
      Wr_h, br_h, Wr_c, br_c, hd0, cD);

  // pre1 = (hs_f + hs_r) @ W1^T + b1   (MFMA)
  gemm_mfma_k<1><<<dim3(256, 8), 256, 0, stream>>>(hs_f, hs_r, w1h, b1, pre1h);

  // decoder: persistent full-M MFMA, sentinel dataflow sync (64 blocks)
  dec_coop_k<<<64, 256, 0, stream>>>(hd0, cD, whhD, bD, hdec);

  // Q = Hdec @ W2^T + b2   (MFMA)
  gemm_mfma_k<0><<<dim3(256, 8), 256, 0, stream>>>(hdec, nullptr, w2h, b2, Qmh);

  // attention (exp-product tanh, transposed staging + float4 reads)
  attn_k<<<dim3(32, 32, 32), 256, 0, stream>>>(pre1h, Qmh, vt, bvt, sumv, out);
}

// Round 19
// 3289.638 us; speedup vs baseline: 1.8498x; 1.0124x over previous
//
#include <hip/hip_runtime.h>
#include <hip/hip_bf16.h>
#include <cstdint>
#include <cstddef>

#define B_ 32
#define S_ 512
#define D_ 256
#define H_ 512

typedef _Float16 h2 __attribute__((ext_vector_type(2)));
typedef _Float16 h4 __attribute__((ext_vector_type(4)));
typedef _Float16 h8 __attribute__((ext_vector_type(8)));
typedef float f32x4 __attribute__((ext_vector_type(4)));
typedef unsigned u32x4 __attribute__((ext_vector_type(4)));

__device__ __forceinline__ h2 H2(unsigned u) { return __builtin_bit_cast(h2, u); }
__device__ __forceinline__ unsigned U2(h2 v) { return __builtin_bit_cast(unsigned, v); }

#if __has_builtin(__builtin_amdgcn_exp2f)
__device__ __forceinline__ float exp2_fast(float x) { return __builtin_amdgcn_exp2f(x); }
#else
__device__ __forceinline__ float exp2_fast(float x) { return exp2f(x); }
#endif
#if __has_builtin(__builtin_amdgcn_rcpf)
__device__ __forceinline__ float rcp_fast(float x) { return __builtin_amdgcn_rcpf(x); }
#else
__device__ __forceinline__ float rcp_fast(float x) { return 1.0f / x; }
#endif

__device__ __forceinline__ float sigm(float x) {
  return rcp_fast(1.0f + exp2_fast(-1.4426950408889634f * x));
}
__device__ __forceinline__ float tanh_fast(float x) {
  return 1.0f - 2.0f * rcp_fast(1.0f + exp2_fast(2.8853900817779268f * x));
}

// Coherent 16B load (bypass L1/L2, read L3). MUST be drained (vm_drain)
// IMMEDIATELY after issue (the compiler does not model vmcnt for inline-asm
// outputs -- r16 lesson).
__device__ __forceinline__ uint4 coh_load16(const void* p) {
  u32x4 v;
  asm volatile("global_load_dwordx4 %0, %1, off sc0 sc1"
               : "=v"(v) : "v"(p) : "memory");
  return __builtin_bit_cast(uint4, v);
}
__device__ __forceinline__ void vm_drain() {
  asm volatile("s_waitcnt vmcnt(0)" ::: "memory");
}

// Sentinel = 0xFFFF per fp16 (a NaN). Legal h values are sigm*tanh in (-1,1).
__device__ __forceinline__ bool valid16(uint4 v) {
  return ((v.x & 0xFFFFu) != 0xFFFFu) && ((v.x >> 16) != 0xFFFFu) &&
         ((v.y & 0xFFFFu) != 0xFFFFu) && ((v.y >> 16) != 0xFFFFu) &&
         ((v.z & 0xFFFFu) != 0xFFFFu) && ((v.z >> 16) != 0xFFFFu) &&
         ((v.w & 0xFFFFu) != 0xFFFFu) && ((v.w >> 16) != 0xFFFFu);
}

__device__ __forceinline__ void h_store(unsigned short* p, unsigned short v) {
  __hip_atomic_store(p, v, __ATOMIC_RELAXED, __HIP_MEMORY_SCOPE_AGENT);
}

// ---------------- fused preamble: sentinel fill + all fp32->fp16 converts ---
#define N_X   1048576u
#define N_WIH 131072u
#define N_WHH 262144u
#define N_W1  65536u
#define C0_ N_X
#define C1_ (C0_ + N_WIH)
#define C2_ (C1_ + N_WIH)
#define C3_ (C2_ + N_WHH)
#define C4_ (C3_ + N_WHH)
#define C5_ (C4_ + N_WHH)
#define C6_ (C5_ + N_W1)
#define NCV (C6_ + N_W1)
__global__ __launch_bounds__(256) void prep_k(
    const float* __restrict__ x,
    const float* __restrict__ WihF, const float* __restrict__ WihR,
    const float* __restrict__ WhhF, const float* __restrict__ WhhR,
    const float* __restrict__ WhhD,
    const float* __restrict__ W1, const float* __restrict__ W2,
    _Float16* __restrict__ xh, _Float16* __restrict__ wihF, _Float16* __restrict__ wihR,
    _Float16* __restrict__ whhF, _Float16* __restrict__ whhR, _Float16* __restrict__ whhD,
    _Float16* __restrict__ w1h, _Float16* __restrict__ w2h,
    uint4* __restrict__ sent)
{
  const size_t stride = (size_t)gridDim.x * 256;
  const size_t NS = 3ull * S_ * B_ * H_ / 8;
  uint4 sv = {0xFFFFFFFFu, 0xFFFFFFFFu, 0xFFFFFFFFu, 0xFFFFFFFFu};
  for (size_t j = (size_t)blockIdx.x * 256 + threadIdx.x; j < NS; j += stride)
    sent[j] = sv;
  for (size_t j = (size_t)blockIdx.x * 256 + threadIdx.x; j < NCV; j += stride) {
    const float* src; _Float16* dst; size_t off;
    if (j < C0_)      { src = x;    dst = xh;   off = j; }
    else if (j < C1_) { src = WihF; dst = wihF; off = j - C0_; }
    else if (j < C2_) { src = WihR; dst = wihR; off = j - C1_; }
    else if (j < C3_) { src = WhhF; dst = whhF; off = j - C2_; }
    else if (j < C4_) { src = WhhR; dst = whhR; off = j - C3_; }
    else if (j < C5_) { src = WhhD; dst = whhD; off = j - C4_; }
    else if (j < C6_) { src = W1;   dst = w1h;  off = j - C5_; }
    else              { src = W2;   dst = w2h;  off = j - C6_; }
    float4 v = ((const float4*)src)[off];
    h4 o = {(_Float16)v.x, (_Float16)v.y, (_Float16)v.z, (_Float16)v.w};
    ((h4*)dst)[off] = o;
  }
}

// ---------------- persistent encoder: full-M MFMA + sentinel sync -----------
__global__ __launch_bounds__(256, 1) void enc_coop_k(
    const _Float16* __restrict__ xh,
    const _Float16* __restrict__ WihF, const _Float16* __restrict__ WhhF, const float* __restrict__ bF,
    const _Float16* __restrict__ WihR, const _Float16* __restrict__ WhhR, const float* __restrict__ bR,
    float* __restrict__ cF, float* __restrict__ cR,
    _Float16* __restrict__ hsF, _Float16* __restrict__ hsR)
{
  __shared__ __align__(16) _Float16 cbuf[96][16][8];
  __shared__ float zfin[4][16][17];
  __shared__ float cls[16][17];

  const int bid = blockIdx.x;
  const int group = bid >> 5;
  const int dir = group >> 1;
  const int bh0 = (group & 1) << 4;
  const int jb = bid & 31;
  const int c0 = jb << 4;
  const int tid = threadIdx.x;
  const int lane = tid & 63;
  const int wv = tid >> 6;

  const _Float16* __restrict__ Wih = dir ? WihR : WihF;
  const _Float16* __restrict__ Whh = dir ? WhhR : WhhF;
  const float* __restrict__ bias = dir ? bR : bF;
  _Float16* __restrict__ hs = dir ? hsR : hsF;
  float* __restrict__ cOut = dir ? cR : cF;

  h8 aw[24];
  {
    const int m = lane & 15, kg = lane >> 4;
    const int wrow = wv * H_ + c0 + m;
    const _Float16* wi = Wih + (size_t)wrow * D_;
    const _Float16* wh = Whh + (size_t)wrow * H_;
    #pragma unroll
    for (int tu = 0; tu < 24; ++tu) {
      int k = tu * 32 + kg * 8;
      aw[tu] = (k < 256) ? *(const h8*)(wi + k) : *(const h8*)(wh + (k - 256));
    }
  }

  const int cc = tid & 15, cb = tid >> 4;
  float bvg[4];
  #pragma unroll
  for (int g = 0; g < 4; ++g) bvg[g] = bias[g * H_ + c0 + cc];

  const char* cbase = (const char*)cbuf + (size_t)((lane >> 4) * 256 + (lane & 15) * 16);
  const int sn = tid & 15;
  const int xo = (tid >> 4) * 2;
  const int ho = (tid >> 4) * 4;
  __syncthreads();

  for (int t = 0; t < S_; ++t) {
    const int xi = dir ? (S_ - 1 - t) : t;

    {
      const _Float16* xp = xh + ((size_t)(bh0 + sn) * S_ + xi) * D_;
      uint4 v0 = *(const uint4*)(xp + xo * 8);
      uint4 v1 = *(const uint4*)(xp + xo * 8 + 8);
      *(uint4*)&cbuf[xo][sn][0] = v0;
      *(uint4*)&cbuf[xo + 1][sn][0] = v1;
    }
    __syncthreads();

    f32x4 acc0 = {0.f, 0.f, 0.f, 0.f}, acc1 = {0.f, 0.f, 0.f, 0.f};
    #pragma unroll
    for (int tu = 0; tu < 8; tu += 2) {
      h8 b0 = *(const h8*)(cbase + tu * 1024);
      h8 b1 = *(const h8*)(cbase + (tu + 1) * 1024);
      acc0 = __builtin_amdgcn_mfma_f32_16x16x32_f16(aw[tu], b0, acc0, 0, 0, 0);
      acc1 = __builtin_amdgcn_mfma_f32_16x16x32_f16(aw[tu + 1], b1, acc1, 0, 0, 0);
    }

    {
      if (t == 0) {
        uint4 z = {0, 0, 0, 0};
        #pragma unroll
        for (int u = 0; u < 4; ++u) *(uint4*)&cbuf[32 + ho + u][sn][0] = z;
      } else {
        const int xip = dir ? xi + 1 : xi - 1;
        const _Float16* hbase = hs + ((size_t)xip * B_ + bh0 + sn) * H_;
        uint4 vs[4];
        unsigned pend = 0xF;
        do {
          #pragma unroll
          for (int u = 0; u < 4; ++u)
            if (pend & (1u << u)) vs[u] = coh_load16(hbase + (ho + u) * 8);
          vm_drain();
          #pragma unroll
          for (int u = 0; u < 4; ++u)
            if ((pend & (1u << u)) && valid16(vs[u])) pend &= ~(1u << u);
        } while (pend);
        #pragma unroll
        for (int u = 0; u < 4; ++u) *(uint4*)&cbuf[32 + ho + u][sn][0] = vs[u];
      }
    }
    __syncthreads();

    #pragma unroll
    for (int tu = 8; tu < 24; tu += 2) {
      h8 b0 = *(const h8*)(cbase + tu * 1024);
      h8 b1 = *(const h8*)(cbase + (tu + 1) * 1024);
      acc0 = __builtin_amdgcn_mfma_f32_16x16x32_f16(aw[tu], b0, acc0, 0, 0, 0);
      acc1 = __builtin_amdgcn_mfma_f32_16x16x32_f16(aw[tu + 1], b1, acc1, 0, 0, 0);
    }
    {
      const int mrow = (lane >> 4) * 4, n = lane & 15;
      #pragma unroll
      for (int r = 0; r < 4; ++r) zfin[wv][mrow + r][n] = acc0[r] + acc1[r];
    }
    __syncthreads();

    {
      const float zi = zfin[0][cc][cb] + bvg[0];
      const float zf = zfin[1][cc][cb] + bvg[1];
      const float zg = zfin[2][cc][cb] + bvg[2];
      const float zo = zfin[3][cc][cb] + bvg[3];
      const float c_old = (t == 0) ? 0.f : cls[cc][cb];
      const float cn = sigm(zf) * c_old + sigm(zi) * tanh_fast(zg);
      const float hn = sigm(zo) * tanh_fast(cn);
      cls[cc][cb] = cn;
      _Float16 hh = (_Float16)hn;
      h_store((unsigned short*)(hs + ((size_t)xi * B_ + bh0 + cb) * H_ + c0 + cc),
              __builtin_bit_cast(unsigned short, hh));
      if (t == S_ - 1) cOut[(size_t)(bh0 + cb) * H_ + c0 + cc] = cn;
    }
  }
}

// ---------------- fused decoder + pre1 GEMM ---------------------------------
// Blocks 0..63: persistent decoder (2 groups x 32 blocks of 16 h-cols).
// Blocks 64..2111: pre1 = (hs_f + hs_r) @ W1^T + b1 (64x64 MFMA tiles),
// filling the 192 CUs the decoder leaves idle.
__global__ __launch_bounds__(256, 1) void dec_fused_k(
    const float* __restrict__ hd0, const float* __restrict__ cD0,
    const _Float16* __restrict__ Whh, const float* __restrict__ bias,
    _Float16* __restrict__ hdec,
    const _Float16* __restrict__ A1, const _Float16* __restrict__ A2,
    const _Float16* __restrict__ W1, const float* __restrict__ b1,
    _Float16* __restrict__ pre1)
{
  __shared__ __align__(16) _Float16 cbuf[64][16][8];   // dec path (16KB)
  __shared__ float zfin[4][16][17];
  __shared__ float cls[16][17];
  // GEMM path aliases cbuf's space via its own arrays (union via extern not
  // needed: totals stay under LDS budget).
  __shared__ __align__(16) _Float16 Abuf[4][66][8];
  __shared__ __align__(16) _Float16 Bbuf[4][66][8];

  const int tid = threadIdx.x;
  const int lane = tid & 63;
  const int wv = tid >> 6;

  if (blockIdx.x >= 64) {
    // ---- pre1 GEMM tile ----
    const int gb = blockIdx.x - 64;
    const int m0 = (gb >> 3) * 64, n0 = (gb & 7) * 64;
    const int sr = tid >> 2, sk = tid & 3;
    f32x4 acc[4] = {{0.f,0.f,0.f,0.f},{0.f,0.f,0.f,0.f},
                    {0.f,0.f,0.f,0.f},{0.f,0.f,0.f,0.f}};
    for (int kc = 0; kc < H_; kc += 32) {
      __syncthreads();
      {
        uint4 a = *(const uint4*)(A1 + (size_t)(m0 + sr) * H_ + kc + sk * 8);
        uint4 a2 = *(const uint4*)(A2 + (size_t)(m0 + sr) * H_ + kc + sk * 8);
        a.x = U2(H2(a.x) + H2(a2.x)); a.y = U2(H2(a.y) + H2(a2.y));
        a.z = U2(H2(a.z) + H2(a2.z)); a.w = U2(H2(a.w) + H2(a2.w));
        *(uint4*)&Abuf[sk][sr][0] = a;
        uint4 b = *(const uint4*)(W1 + (size_t)(n0 + sr) * H_ + kc + sk * 8);
        *(uint4*)&Bbuf[sk][sr][0] = b;
      }
      __syncthreads();
      const int fr = lane & 15, kg = lane >> 4;
      h8 af = *(const h8*)&Abuf[kg][wv * 16 + fr][0];
      #pragma unroll
      for (int nt = 0; nt < 4; ++nt) {
        h8 bf = *(const h8*)&Bbuf[kg][nt * 16 + fr][0];
        acc[nt] = __builtin_amdgcn_mfma_f32_16x16x32_f16(af, bf, acc[nt], 0, 0, 0);
      }
    }
    const int fr = lane & 15, fq = lane >> 4;
    #pragma unroll
    for (int nt = 0; nt < 4; ++nt) {
      const int n = n0 + nt * 16 + fr;
      const float bv = b1[n];
      #pragma unroll
      for (int r = 0; r < 4; ++r) {
        const int m = m0 + wv * 16 + fq * 4 + r;
        pre1[(size_t)m * H_ + n] = (_Float16)(acc[nt][r] + bv);
      }
    }
    return;
  }

  // ---- decoder path (blocks 0..63) ----
  const int bid = blockIdx.x;
  const int group = bid >> 5;
  const int bh0 = group << 4;
  const int jb = bid & 31;
  const int c0 = jb << 4;

  h8 aw[16];
  {
    const int m = lane & 15, kg = lane >> 4;
    const _Float16* wh = Whh + (size_t)(wv * H_ + c0 + m) * H_;
    #pragma unroll
    for (int tu = 0; tu < 16; ++tu) aw[tu] = *(const h8*)(wh + tu * 32 + kg * 8);
  }

  const int cc = tid & 15, cb = tid >> 4;
  float bvg[4];
  #pragma unroll
  for (int g = 0; g < 4; ++g) bvg[g] = bias[g * H_ + c0 + cc];
  cls[cc][cb] = cD0[(size_t)(bh0 + cb) * H_ + c0 + cc];

  const char* cbase = (const char*)cbuf + (size_t)((lane >> 4) * 256 + (lane & 15) * 16);
  const int sn = tid & 15, ho = (tid >> 4) * 4;
  __syncthreads();

  for (int t = 0; t < S_; ++t) {
    {
      if (t == 0) {
        const float* src = hd0 + (size_t)(bh0 + sn) * H_;
        #pragma unroll
        for (int u = 0; u < 4; ++u) {
          float4 f0 = *(const float4*)(src + (ho + u) * 8);
          float4 f1 = *(const float4*)(src + (ho + u) * 8 + 4);
          h8 o = {(_Float16)f0.x, (_Float16)f0.y, (_Float16)f0.z, (_Float16)f0.w,
                  (_Float16)f1.x, (_Float16)f1.y, (_Float16)f1.z, (_Float16)f1.w};
          *(h8*)&cbuf[ho + u][sn][0] = o;
        }
      } else {
        const _Float16* src = hdec + ((size_t)(t - 1) * B_ + bh0 + sn) * H_;
        uint4 vs[4];
        unsigned pend = 0xF;
        do {
          #pragma unroll
          for (int u = 0; u < 4; ++u)
            if (pend & (1u << u)) vs[u] = coh_load16(src + (ho + u) * 8);
          vm_drain();
          #pragma unroll
          for (int u = 0; u < 4; ++u)
            if ((pend & (1u << u)) && valid16(vs[u])) pend &= ~(1u << u);
        } while (pend);
        #pragma unroll
        for (int u = 0; u < 4; ++u) *(uint4*)&cbuf[ho + u][sn][0] = vs[u];
      }
    }
    __syncthreads();

    f32x4 acc0 = {0.f, 0.f, 0.f, 0.f}, acc1 = {0.f, 0.f, 0.f, 0.f};
    #pragma unroll
    for (int tu = 0; tu < 16; tu += 2) {
      h8 b0 = *(const h8*)(cbase + tu * 1024);
      h8 b1 = *(const h8*)(cbase + (tu + 1) * 1024);
      acc0 = __builtin_amdgcn_mfma_f32_16x16x32_f16(aw[tu], b0, acc0, 0, 0, 0);
      acc1 = __builtin_amdgcn_mfma_f32_16x16x32_f16(aw[tu + 1], b1, acc1, 0, 0, 0);
    }
    {
      const int mrow = (lane >> 4) * 4, n = lane & 15;
      #pragma unroll
      for (int r = 0; r < 4; ++r) zfin[wv][mrow + r][n] = acc0[r] + acc1[r];
    }
    __syncthreads();

    {
      const float zi = zfin[0][cc][cb] + bvg[0];
      const float zf = zfin[1][cc][cb] + bvg[1];
      const float zg = zfin[2][cc][cb] + bvg[2];
      const float zo = zfin[3][cc][cb] + bvg[3];
      const float cn = sigm(zf) * cls[cc][cb] + sigm(zi) * tanh_fast(zg);
      const float hn = sigm(zo) * tanh_fast(cn);
      cls[cc][cb] = cn;
      _Float16 hh = (_Float16)hn;
      h_store((unsigned short*)(hdec + ((size_t)t * B_ + bh0 + cb) * H_ + c0 + cc),
              __builtin_bit_cast(unsigned short, hh));
    }
  }
}

// ---------------- MFMA tiled GEMM: C[M,512] = A @ W^T + bias (Q path) -------
__global__ __launch_bounds__(256) void gemm_mfma_k(
    const _Float16* __restrict__ A1,
    const _Float16* __restrict__ W, const float* __restrict__ bias,
    _Float16* __restrict__ C)
{
  __shared__ __align__(16) _Float16 Abuf[4][66][8];
  __shared__ __align__(16) _Float16 Bbuf[4][66][8];
  const int tid = threadIdx.x;
  const int m0 = blockIdx.x * 64, n0 = blockIdx.y * 64;
  const int lane = tid & 63, wv = tid >> 6;
  const int sr = tid >> 2, sk = tid & 3;
  f32x4 acc[4] = {{0.f,0.f,0.f,0.f},{0.f,0.f,0.f,0.f},
                  {0.f,0.f,0.f,0.f},{0.f,0.f,0.f,0.f}};

  for (int kc = 0; kc < H_; kc += 32) {
    __syncthreads();
    {
      uint4 a = *(const uint4*)(A1 + (size_t)(m0 + sr) * H_ + kc + sk * 8);
      *(uint4*)&Abuf[sk][sr][0] = a;
      uint4 b = *(const uint4*)(W + (size_t)(n0 + sr) * H_ + kc + sk * 8);
      *(uint4*)&Bbuf[sk][sr][0] = b;
    }
    __syncthreads();
    const int fr = lane & 15, kg = lane >> 4;
    h8 af = *(const h8*)&Abuf[kg][wv * 16 + fr][0];
    #pragma unroll
    for (int nt = 0; nt < 4; ++nt) {
      h8 bf = *(const h8*)&Bbuf[kg][nt * 16 + fr][0];
      acc[nt] = __builtin_amdgcn_mfma_f32_16x16x32_f16(af, bf, acc[nt], 0, 0, 0);
    }
  }
  const int fr = lane & 15, fq = lane >> 4;
  #pragma unroll
  for (int nt = 0; nt < 4; ++nt) {
    const int n = n0 + nt * 16 + fr;
    const float bv = bias[n];
    #pragma unroll
    for (int r = 0; r < 4; ++r) {
      const int m = m0 + wv * 16 + fq * 4 + r;
      C[(size_t)m * H_ + n] = (_Float16)(acc[nt][r] + bv);
    }
  }
}

__device__ __forceinline__ float4 load4f(const float* p) { return *(const float4*)p; }
__device__ __forceinline__ float4 load4f(const _Float16* p) {
  uint2 u = *(const uint2*)p;
  h2 a = H2(u.x), b = H2(u.y);
  return make_float4((float)a.x, (float)a.y, (float)b.x, (float)b.y);
}

// merged decoder-init: y<16 -> hd0; y>=16 -> cD
__global__ __launch_bounds__(256) void dec_init_k(
    const _Float16* __restrict__ hfl, const _Float16* __restrict__ hr,
    const float* __restrict__ cF, const float* __restrict__ cR,
    const float* __restrict__ Wr_h, const float* __restrict__ br_h,
    const float* __restrict__ Wr_c, const float* __restrict__ br_c,
    float* __restrict__ hd0, float* __restrict__ cD)
{
  const int tid = threadIdx.x;
  const int col = tid & 31;
  const int rg  = tid >> 5;
  const int which = (int)blockIdx.y >> 4;
  const int n = ((int)blockIdx.y & 15) * 32 + col;
  const float* W = which ? Wr_c : Wr_h;
  const float* bias = which ? br_c : br_h;
  float* C = which ? cD : hd0;
  float acc[4] = {0, 0, 0, 0};
  #pragma unroll
  for (int pass = 0; pass < 2; ++pass) {
    const float4* __restrict__ w4 = (const float4*)(W + (size_t)n * 1024 + pass * 512);
    if (which) {
      const float* A = pass ? cR : cF;
      for (int k4 = 0; k4 < 128; ++k4) {
        float4 w = w4[k4];
        #pragma unroll
        for (int i = 0; i < 4; ++i) {
          int row = rg + (i << 3);
          float4 a = load4f(A + (size_t)row * H_ + k4 * 4);
          acc[i] += w.x * a.x + w.y * a.y + w.z * a.z + w.w * a.w;
        }
      }
    } else {
      const _Float16* A = pass ? hr : hfl;
      for (int k4 = 0; k4 < 128; ++k4) {
        float4 w = w4[k4];
        #pragma unroll
        for (int i = 0; i < 4; ++i) {
          int row = rg + (i << 3);
          float4 a = load4f(A + (size_t)row * H_ + k4 * 4);
          acc[i] += w.x * a.x + w.y * a.y + w.z * a.z + w.w * a.w;
        }
      }
    }
  }
  const float bv = bias[n];
  #pragma unroll
  for (int i = 0; i < 4; ++i) {
    int row = rg + (i << 3);
    C[(size_t)row * H_ + n] = acc[i] + bv;
  }
}

__global__ __launch_bounds__(256) void sumv_k(const float* __restrict__ vt,
                                              float* __restrict__ o) {
  __shared__ float sh[4];
  float v = vt[threadIdx.x] + vt[threadIdx.x + 256];
  #pragma unroll
  for (int d = 32; d; d >>= 1) v += __shfl_down(v, d, 64);
  if ((threadIdx.x & 63) == 0) sh[threadIdx.x >> 6] = v;
  __syncthreads();
  if (threadIdx.x == 0) o[0] = sh[0] + sh[1] + sh[2] + sh[3];
}

// logits[b,t,s] = (sumv + bvt) - 2 * sum_h v[h] * rcp(Ep[s,h]*Eq[t,h] + 1)
#define KT_ 2.8853900817779268f
__global__ __launch_bounds__(256) void attn_k(
    const _Float16* __restrict__ pre1, const _Float16* __restrict__ Qm,
    const float* __restrict__ vt, const float* __restrict__ bvt,
    const float* __restrict__ sumv, float* __restrict__ out)
{
  __shared__ float sp[16][260];
  __shared__ float sq[16][260];
  __shared__ float sv[256];
  const int b = blockIdx.z, tbase = blockIdx.y << 4, sbase = blockIdx.x << 4;
  const int tid = threadIdx.x;
  const int so = tid & 15, to = tid >> 4;
  float acc0 = 0.f, acc1 = 0.f;
  const float cfin = sumv[0] + bvt[0];

  for (int h0 = 0; h0 < H_; h0 += 256) {
    __syncthreads();
    {
      const int i = tid & 15, hoo = (tid >> 4) * 16;
      const _Float16* qp = Qm + ((size_t)(tbase + i) * B_ + b) * H_ + h0 + hoo;
      const _Float16* pp = pre1 + ((size_t)(sbase + i) * B_ + b) * H_ + h0 + hoo;
      h8 q0 = *(const h8*)qp, q1 = *(const h8*)(qp + 8);
      h8 p0 = *(const h8*)pp, p1 = *(const h8*)(pp + 8);
      #pragma unroll
      for (int j = 0; j < 8; ++j) {
        sq[i][hoo + j]     = exp2_fast(fminf(fmaxf(KT_ * (float)q0[j], -60.f), 60.f));
        sq[i][hoo + 8 + j] = exp2_fast(fminf(fmaxf(KT_ * (float)q1[j], -60.f), 60.f));
        sp[i][hoo + j]     = exp2_fast(fminf(fmaxf(KT_ * (float)p0[j], -60.f), 60.f));
        sp[i][hoo + 8 + j] = exp2_fast(fminf(fmaxf(KT_ * (float)p1[j], -60.f), 60.f));
      }
    }
    sv[tid] = vt[h0 + tid];
    __syncthreads();
    #pragma unroll 8
    for (int h4_ = 0; h4_ < 64; ++h4_) {
      float4 p = *(const float4*)&sp[so][h4_ * 4];
      float4 q = *(const float4*)&sq[to][h4_ * 4];
      float4 vv = *(const float4*)&sv[h4_ * 4];
      acc0 = fmaf(vv.x, rcp_fast(fmaf(p.x, q.x, 1.0f)), acc0);
      acc1 = fmaf(vv.y, rcp_fast(fmaf(p.y, q.y, 1.0f)), acc1);
      acc0 = fmaf(vv.z, rcp_fast(fmaf(p.z, q.z, 1.0f)), acc0);
      acc1 = fmaf(vv.w, rcp_fast(fmaf(p.w, q.w, 1.0f)), acc1);
    }
  }
  out[((size_t)b * S_ + tbase + to) * S_ + sbase + so] = cfin - 2.f * (acc0 + acc1);
}

extern "C" void kernel_launch(void* const* d_in, const int* in_sizes, int n_in,
                              void* d_out, int out_size, void* d_ws, size_t ws_size,
                              hipStream_t stream)
{
  (void)in_sizes; (void)n_in; (void)out_size; (void)ws_size;
  const float* x     = (const float*)d_in[0];
  const float* WihF  = (const float*)d_in[1];
  const float* WhhF  = (const float*)d_in[2];
  const float* bF    = (const float*)d_in[3];
  const float* WihR  = (const float*)d_in[4];
  const float* WhhR  = (const float*)d_in[5];
  const float* bR    = (const float*)d_in[6];
  /* d_in[7] = Wih_d unused by reference decoder */
  const float* WhhD  = (const float*)d_in[8];
  const float* bD    = (const float*)d_in[9];
  const float* Wr_h  = (const float*)d_in[10];
  const float* br_h  = (const float*)d_in[11];
  const float* Wr_c  = (const float*)d_in[12];
  const float* br_c  = (const float*)d_in[13];
  const float* W1    = (const float*)d_in[14];
  const float* b1    = (const float*)d_in[15];
  const float* W2    = (const float*)d_in[16];
  const float* b2    = (const float*)d_in[17];
  const float* vt    = (const float*)d_in[18];
  const float* bvt   = (const float*)d_in[19];
  float* out = (float*)d_out;

  const size_t SBH = (size_t)S_ * B_ * H_;
  const size_t BH  = (size_t)B_ * H_;

  _Float16* hp = (_Float16*)d_ws;
  _Float16* hs_f  = hp;              hp += SBH;
  _Float16* hs_r  = hp;              hp += SBH;
  _Float16* hdec  = hp;              hp += SBH;
  _Float16* pre1h = hp;              hp += SBH;
  _Float16* Qmh   = hp;              hp += SBH;
  _Float16* xh    = hp;              hp += (size_t)B_ * S_ * D_;
  _Float16* wihF  = hp;              hp += (size_t)4 * H_ * D_;
  _Float16* wihR  = hp;              hp += (size_t)4 * H_ * D_;
  _Float16* whhF  = hp;              hp += (size_t)4 * H_ * H_;
  _Float16* whhR  = hp;              hp += (size_t)4 * H_ * H_;
  _Float16* whhD  = hp;              hp += (size_t)4 * H_ * H_;
  _Float16* w1h   = hp;              hp += (size_t)H_ * H_;
  _Float16* w2h   = hp;              hp += (size_t)H_ * H_;
  float* fp  = (float*)hp;
  float* cF  = fp;                   fp += BH;
  float* cR  = fp;                   fp += BH;
  float* cD  = fp;                   fp += BH;
  float* hd0 = fp;                   fp += BH;
  float* sumv = fp;

  // fused preamble
  prep_k<<<2048, 256, 0, stream>>>(x, WihF, WihR, WhhF, WhhR, WhhD, W1, W2,
                                   xh, wihF, wihR, whhF, whhR, whhD, w1h, w2h,
                                   (uint4*)hs_f);
  sumv_k<<<1, 256, 0, stream>>>(vt, sumv);

  // encoder: persistent full-M MFMA, sentinel dataflow sync
  enc_coop_k<<<128, 256, 0, stream>>>(xh, wihF, whhF, bF, wihR, whhR, bR,
                                      cF, cR, hs_f, hs_r);

  // decoder init (merged hd0 + cD)
  dec_init_k<<<dim3(1, 32), 256, 0, stream>>>(
      hs_f + (size_t)(S_ - 1) * BH, hs_r, cF, cR,
      Wr_h, br_h, Wr_c, br_c, hd0, cD);

  // fused: decoder (blocks 0..63) + pre1 GEMM (blocks 64..2111)
  dec_fused_k<<<64 + 2048, 256, 0, stream>>>(hd0, cD, whhD, bD, hdec,
                                             hs_f, hs_r, w1h, b1, pre1h);

  // Q = Hdec @ W2^T + b2
  gemm_mfma_k<<<dim3(256, 8), 256, 0, stream>>>(hdec, w2h, b2, Qmh);

  // attention
  attn_k<<<dim3(32, 32, 32), 256, 0, stream>>>(pre1h, Qmh, vt, bvt, sumv, out);
}